// Round 4
// baseline (768.904 us; speedup 1.0000x reference)
//
#include <hip/hip_runtime.h>

#define N_NODE 100000
#define EMB 112
#define BATCH 512
#define SEQL 50
#define NNZ 1600000
#define NROWS (BATCH * SEQL)          // 25600 flattened session slots

#define SCAN_CHUNK 1024
#define SCAN_NBLK ((N_NODE + SCAN_CHUNK - 1) / SCAN_CHUNK)   // 98

#define BSHIFT 6
#define NBUCK ((N_NODE + (1 << BSHIFT) - 1) >> BSHIFT)       // 1563

// ---------------- CSR build ------------------------------------------------
__global__ __launch_bounds__(256) void csr_count(
    const int* __restrict__ rows, int* __restrict__ counts)
{
    int e = blockIdx.x * 256 + threadIdx.x;
    if (e < NNZ) atomicAdd(&counts[rows[e]], 1);
}

__global__ __launch_bounds__(256) void csr_scan1(
    const int* __restrict__ counts, int* __restrict__ row_start,
    int* __restrict__ blk_sums)
{
    __shared__ int lsum[256];
    const int tid = threadIdx.x;
    const int base = blockIdx.x * SCAN_CHUNK + tid * 4;
    int local[4], s = 0;
    for (int j = 0; j < 4; ++j) {
        int idx = base + j;
        int v = (idx < N_NODE) ? counts[idx] : 0;
        local[j] = s;
        s += v;
    }
    lsum[tid] = s;
    __syncthreads();
    for (int off = 1; off < 256; off <<= 1) {
        int t = (tid >= off) ? lsum[tid - off] : 0;
        __syncthreads();
        lsum[tid] += t;
        __syncthreads();
    }
    int thread_excl = lsum[tid] - s;
    for (int j = 0; j < 4; ++j) {
        int idx = base + j;
        if (idx < N_NODE) row_start[idx] = thread_excl + local[j];
    }
    if (tid == 255) blk_sums[blockIdx.x] = lsum[255];
}

__global__ __launch_bounds__(128) void csr_scan2(
    const int* __restrict__ blk_sums, int* __restrict__ blk_off)
{
    __shared__ int s[128];
    const int tid = threadIdx.x;
    int v = (tid < SCAN_NBLK) ? blk_sums[tid] : 0;
    s[tid] = v;
    __syncthreads();
    for (int off = 1; off < 128; off <<= 1) {
        int t = (tid >= off) ? s[tid - off] : 0;
        __syncthreads();
        s[tid] += t;
        __syncthreads();
    }
    if (tid < SCAN_NBLK) blk_off[tid] = s[tid] - v;
}

__global__ __launch_bounds__(256) void csr_scan3(
    int* __restrict__ row_start, const int* __restrict__ blk_off)
{
    int idx = blockIdx.x * SCAN_CHUNK + threadIdx.x * 4;
    int off = blk_off[blockIdx.x];
    for (int j = 0; j < 4; ++j)
        if (idx + j < N_NODE) row_start[idx + j] += off;
}

// ---- pass 1: append edges into 64-row bucket regions (frontier writes) ----
__global__ __launch_bounds__(256) void bucket_scatter(
    const int* __restrict__ rows, const int* __restrict__ cols,
    const float* __restrict__ vals, const int* __restrict__ row_start,
    int* __restrict__ bcur, uint2* __restrict__ staged)
{
    int e = blockIdx.x * 256 + threadIdx.x;
    if (e >= NNZ) return;
    int r = rows[e];
    int b = r >> BSHIFT;
    int base = row_start[b << BSHIFT];
    int slot = base + atomicAdd(&bcur[b], 1);
    uint2 s;
    s.x = ((unsigned)(r & 63) << 26) | (unsigned)cols[e];
    s.y = __float_as_uint(vals[e]);
    staged[slot] = s;
}

// ---- pass 2: within-bucket scatter to exact CSR slot (L2-resident window) -
__global__ __launch_bounds__(256) void csr_scatter2(
    const uint2* __restrict__ staged, const int* __restrict__ row_start,
    int* __restrict__ cursor, int* __restrict__ csr_col,
    float* __restrict__ csr_val)
{
    const int b = blockIdx.x;
    const int beg = row_start[b << BSHIFT];
    const int end = (b == NBUCK - 1) ? NNZ : row_start[(b + 1) << BSHIFT];
    for (int i = beg + threadIdx.x; i < end; i += 256) {
        uint2 s = staged[i];
        int row = (b << BSHIFT) | (int)(s.x >> 26);
        int col = (int)(s.x & 0x03FFFFFFu);
        int slot = row_start[row] + atomicAdd(&cursor[row], 1);
        csr_col[slot] = col;
        csr_val[slot] = __uint_as_float(s.y);
    }
}

// mark rows of the embedding table that attention will actually read
__global__ __launch_bounds__(256) void mark_needed(
    const int* __restrict__ items, int* __restrict__ needed)
{
    int i = blockIdx.x * 256 + threadIdx.x;
    if (i >= NROWS) return;
    int g = items[i];
    if (g > 0) needed[g - 1] = 1;     // benign races, all write 1
}

// ---------------- HyperConv layer: wave-per-row segmented sum --------------
// lanes 0..55 each own a float2 feature chunk (112 floats). 4 rows per block.
__global__ __launch_bounds__(256) void spmm_csr(
    const float* __restrict__ src, const int* __restrict__ csr_col,
    const float* __restrict__ csr_val, const int* __restrict__ row_start,
    const int* __restrict__ counts, const int* __restrict__ needed,
    int use_needed, float* __restrict__ out)
{
    const int wave = threadIdx.x >> 6;
    const int lane = threadIdx.x & 63;
    const int row = blockIdx.x * 4 + wave;
    if (row >= N_NODE) return;
    if (use_needed && needed[row] == 0) return;   // wave-uniform exit
    const int beg = row_start[row];
    const int n = counts[row];
    const bool act = lane < 56;
    const int d = lane * 2;
    float ax = 0.f, ay = 0.f;
    int i = 0;
    for (; i + 4 <= n; i += 4) {
        int   c0 = csr_col[beg + i],     c1 = csr_col[beg + i + 1];
        int   c2 = csr_col[beg + i + 2], c3 = csr_col[beg + i + 3];
        float v0 = csr_val[beg + i],     v1 = csr_val[beg + i + 1];
        float v2 = csr_val[beg + i + 2], v3 = csr_val[beg + i + 3];
        if (act) {
            float2 x0 = *(const float2*)(src + (size_t)c0 * EMB + d);
            float2 x1 = *(const float2*)(src + (size_t)c1 * EMB + d);
            float2 x2 = *(const float2*)(src + (size_t)c2 * EMB + d);
            float2 x3 = *(const float2*)(src + (size_t)c3 * EMB + d);
            ax += v0 * x0.x; ay += v0 * x0.y;
            ax += v1 * x1.x; ay += v1 * x1.y;
            ax += v2 * x2.x; ay += v2 * x2.y;
            ax += v3 * x3.x; ay += v3 * x3.y;
        }
    }
    for (; i < n; ++i) {
        int c0 = csr_col[beg + i];
        float v0 = csr_val[beg + i];
        if (act) {
            float2 x0 = *(const float2*)(src + (size_t)c0 * EMB + d);
            ax += v0 * x0.x; ay += v0 * x0.y;
        }
    }
    if (act) {
        float2 r; r.x = ax; r.y = ay;
        *(float2*)(out + (size_t)row * EMB + d) = r;
    }
}

// ---------------- gather + Q/K projection (register-tiled) -----------------
#define GP_ROWS 32
#define SEQ_PAD 116
__global__ __launch_bounds__(256) void gather_project(
    const float* __restrict__ emb0, const float* __restrict__ emb1,
    const float* __restrict__ emb2,
    const int* __restrict__ items,
    const float* __restrict__ Wq, const float* __restrict__ Wk,
    float* __restrict__ seqws, float* __restrict__ Qws, float* __restrict__ Kws)
{
    __shared__ float s_seq[GP_ROWS][SEQ_PAD];
    const int t = threadIdx.x;
    const int R0 = blockIdx.x * GP_ROWS;

    for (int idx = t; idx < GP_ROWS * EMB; idx += 256) {
        int r = idx / EMB, d = idx - r * EMB;
        int g = items[R0 + r];
        float v = 0.f;
        if (g > 0) {
            size_t off = (size_t)(g - 1) * EMB + d;
            v = (emb0[off] + emb1[off] + emb2[off]) * (1.f / 3.f);
        }
        s_seq[r][d] = v;
        seqws[(size_t)(R0 + r) * EMB + d] = v;
    }
    __syncthreads();

    if (t >= 224) return;
    const int rg = t / 28;
    const int e0 = (t % 28) * 4;

    float accq[4][4] = {{0.f}}, acck[4][4] = {{0.f}};
    for (int d4 = 0; d4 < 28; ++d4) {
        float sa[4][4];
        #pragma unroll
        for (int rr = 0; rr < 4; ++rr) {
            float4 v = *(const float4*)&s_seq[rg * 4 + rr][d4 * 4];
            sa[rr][0] = v.x; sa[rr][1] = v.y; sa[rr][2] = v.z; sa[rr][3] = v.w;
        }
        #pragma unroll
        for (int j = 0; j < 4; ++j) {
            const int d = d4 * 4 + j;
            float4 wq = *(const float4*)&Wq[d * EMB + e0];
            float4 wk = *(const float4*)&Wk[d * EMB + e0];
            #pragma unroll
            for (int rr = 0; rr < 4; ++rr) {
                float s = sa[rr][j];
                accq[rr][0] += s * wq.x; accq[rr][1] += s * wq.y;
                accq[rr][2] += s * wq.z; accq[rr][3] += s * wq.w;
                acck[rr][0] += s * wk.x; acck[rr][1] += s * wk.y;
                acck[rr][2] += s * wk.z; acck[rr][3] += s * wk.w;
            }
        }
    }
    #pragma unroll
    for (int rr = 0; rr < 4; ++rr) {
        size_t o = (size_t)(R0 + rg * 4 + rr) * EMB + e0;
        float4 q, k;
        q.x = 1.f / (1.f + __expf(-accq[rr][0]));
        q.y = 1.f / (1.f + __expf(-accq[rr][1]));
        q.z = 1.f / (1.f + __expf(-accq[rr][2]));
        q.w = 1.f / (1.f + __expf(-accq[rr][3]));
        k.x = 1.f / (1.f + __expf(-acck[rr][0]));
        k.y = 1.f / (1.f + __expf(-acck[rr][1]));
        k.z = 1.f / (1.f + __expf(-acck[rr][2]));
        k.w = 1.f / (1.f + __expf(-acck[rr][3]));
        *(float4*)&Qws[o] = q;
        *(float4*)&Kws[o] = k;
    }
}

// ---------------- scores + softmax + pooling (no LDS atomics) --------------
__global__ __launch_bounds__(256) void attn_score_pool(
    const float* __restrict__ Qws, const float* __restrict__ Kws,
    const float* __restrict__ seqws,
    const int* __restrict__ session_len, const float* __restrict__ mask,
    float* __restrict__ seq_h, float* __restrict__ acc2)
{
    __shared__ float sQ[SEQL][SEQ_PAD];
    __shared__ float sK[SEQL][SEQ_PAD];
    __shared__ float s_part[SEQL][4];
    __shared__ float s_mask[SEQL];
    __shared__ float s_beta[SEQL];

    const int b = blockIdx.x;
    const int t = threadIdx.x;

    for (int idx = t; idx < SEQL * (EMB / 4); idx += 256) {
        int l = idx / (EMB / 4), d4 = idx - l * (EMB / 4);
        *(float4*)&sQ[l][d4 * 4] = *(const float4*)&Qws[((size_t)b * SEQL + l) * EMB + d4 * 4];
        *(float4*)&sK[l][d4 * 4] = *(const float4*)&Kws[((size_t)b * SEQL + l) * EMB + d4 * 4];
    }
    if (t < SEQL) s_mask[t] = mask[b * SEQL + t];
    __syncthreads();

    const float inv_sqrt_d = rsqrtf((float)EMB);
    if (t < 200) {
        const int l = t >> 2;
        const int m0 = t & 3;
        float partial = 0.f;
        if (s_mask[l] != 0.f) {
            for (int m = m0; m < SEQL; m += 4) {
                if (m == l || s_mask[m] == 0.f) continue;
                float dot = 0.f;
                for (int d4 = 0; d4 < EMB / 4; ++d4) {
                    float4 a = *(const float4*)&sQ[l][d4 * 4];
                    float4 c = *(const float4*)&sK[m][d4 * 4];
                    dot += a.x * c.x + a.y * c.y + a.z * c.z + a.w * c.w;
                }
                partial += inv_sqrt_d / (1.f + __expf(-dot));
            }
        }
        s_part[l][m0] = partial;
    }
    __syncthreads();

    if (t < 64) {
        float slen = (float)session_len[b];
        float a = -1e30f;
        if (t < SEQL && s_mask[t] > 0.f)
            a = (s_part[t][0] + s_part[t][1] + s_part[t][2] + s_part[t][3]) / slen;
        float mx = a;
        for (int o = 32; o > 0; o >>= 1) mx = fmaxf(mx, __shfl_xor(mx, o));
        float ex = __expf(a - mx);
        float sm = ex;
        for (int o = 32; o > 0; o >>= 1) sm += __shfl_xor(sm, o);
        if (t < SEQL) s_beta[t] = ex / sm;
    }
    __syncthreads();

    if (t < EMB) {
        float h = 0.f;
        for (int l = 0; l < SEQL; ++l)
            h += s_beta[l] * seqws[((size_t)b * SEQL + l) * EMB + t];
        seq_h[b * EMB + t] = h;
        acc2[b * EMB + t] = h;
    }
}

// ---------------- DA = D @ A  (32x32 LDS-tiled) ----------------------------
__global__ __launch_bounds__(256) void gemm_DA(
    const float* __restrict__ D, const float* __restrict__ A,
    float* __restrict__ DA)
{
    __shared__ float sD[32][33];
    __shared__ float sA[32][33];
    const int tx = threadIdx.x & 15;
    const int ty = threadIdx.x >> 4;
    const int i0 = blockIdx.y * 32;
    const int j0 = blockIdx.x * 32;
    float a00 = 0.f, a01 = 0.f, a10 = 0.f, a11 = 0.f;
    for (int k0 = 0; k0 < BATCH; k0 += 32) {
        for (int idx = threadIdx.x; idx < 1024; idx += 256) {
            int r = idx >> 5, c = idx & 31;
            sD[r][c] = D[(i0 + r) * BATCH + k0 + c];
            sA[r][c] = A[(k0 + r) * BATCH + j0 + c];
        }
        __syncthreads();
        #pragma unroll 8
        for (int kk = 0; kk < 32; ++kk) {
            float d0 = sD[2 * ty][kk], d1 = sD[2 * ty + 1][kk];
            float b0 = sA[kk][2 * tx], b1 = sA[kk][2 * tx + 1];
            a00 += d0 * b0; a01 += d0 * b1;
            a10 += d1 * b0; a11 += d1 * b1;
        }
        __syncthreads();
    }
    DA[(i0 + 2 * ty) * BATCH + j0 + 2 * tx] = a00;
    DA[(i0 + 2 * ty) * BATCH + j0 + 2 * tx + 1] = a01;
    DA[(i0 + 2 * ty + 1) * BATCH + j0 + 2 * tx] = a10;
    DA[(i0 + 2 * ty + 1) * BATCH + j0 + 2 * tx + 1] = a11;
}

// ---------------- t = s @ W^T ----------------------------------------------
__global__ __launch_bounds__(128) void sess_linear(
    const float* __restrict__ s, const float* __restrict__ W,
    float* __restrict__ t)
{
    __shared__ float s_row[EMB];
    int b = blockIdx.x;
    int e = threadIdx.x;
    if (e < EMB) s_row[e] = s[b * EMB + e];
    __syncthreads();
    if (e >= EMB) return;
    float acc = 0.f;
    for (int d = 0; d < EMB; ++d) acc += s_row[d] * W[e * EMB + d];
    t[b * EMB + e] = acc;
}

// ---------------- s = DA @ t; acc2 += s/||s||; last: out = acc2/3 ----------
__global__ __launch_bounds__(128) void sess_prop(
    const float* __restrict__ DA, const float* __restrict__ t,
    float* __restrict__ s_out, float* __restrict__ acc2,
    float* __restrict__ out, int is_last)
{
    __shared__ float s_da[BATCH];
    __shared__ float s_sq[128];
    int b = blockIdx.x;
    int e = threadIdx.x;
    for (int k = e; k < BATCH; k += 128) s_da[k] = DA[b * BATCH + k];
    __syncthreads();

    float v = 0.f;
    if (e < EMB) {
        for (int k = 0; k < BATCH; ++k) v += s_da[k] * t[k * EMB + e];
    }
    s_sq[e] = (e < EMB) ? v * v : 0.f;
    __syncthreads();
    for (int off = 64; off > 0; off >>= 1) {
        if (e < off) s_sq[e] += s_sq[e + off];
        __syncthreads();
    }
    float nrm = fmaxf(sqrtf(s_sq[0]), 1e-12f);
    if (e < EMB) {
        float a = acc2[b * EMB + e] + v / nrm;
        acc2[b * EMB + e] = a;
        s_out[b * EMB + e] = v;
        if (is_last) out[b * EMB + e] = a * (1.f / 3.f);
    }
}

extern "C" void kernel_launch(void* const* d_in, const int* in_sizes, int n_in,
                              void* d_out, int out_size, void* d_ws, size_t ws_size,
                              hipStream_t stream)
{
    (void)in_sizes; (void)n_in; (void)out_size; (void)ws_size;

    const float* embedding    = (const float*)d_in[0];
    const float* adj_vals     = (const float*)d_in[1];
    const float* W_q          = (const float*)d_in[2];
    const float* W_k          = (const float*)d_in[3];
    const float* w_sess       = (const float*)d_in[4];
    const float* D            = (const float*)d_in[5];
    const float* A            = (const float*)d_in[6];
    const int*   adj_rows     = (const int*)d_in[7];
    const int*   adj_cols     = (const int*)d_in[8];
    const int*   session_item = (const int*)d_in[9];
    const int*   session_len  = (const int*)d_in[10];
    const float* mask         = (const float*)d_in[11];
    float* out = (float*)d_out;

    // ---- workspace layout (4-byte elems) ----
    float* emb1      = (float*)d_ws;
    float* emb2      = emb1 + (size_t)N_NODE * EMB;
    float* DAb       = emb2 + (size_t)N_NODE * EMB;
    float* seqh      = DAb  + (size_t)BATCH * BATCH;
    float* acc2      = seqh + (size_t)BATCH * EMB;
    float* tbuf      = acc2 + (size_t)BATCH * EMB;
    float* sbuf      = tbuf + (size_t)BATCH * EMB;
    float* seqws     = sbuf + (size_t)BATCH * EMB;
    float* Qws       = seqws + (size_t)NROWS * EMB;
    float* Kws       = Qws   + (size_t)NROWS * EMB;
    int*   counts    = (int*)(Kws + (size_t)NROWS * EMB);
    int*   cursor    = counts + N_NODE;
    int*   needed    = cursor + N_NODE;
    int*   bcur      = needed + N_NODE;          // NBUCK (pad to 2048)
    int*   row_start = bcur + 2048;
    int*   blk_sums  = row_start + N_NODE;
    int*   blk_off   = blk_sums + 128;
    int*   csr_col   = blk_off + 128;
    float* csr_val   = (float*)(csr_col + NNZ);
    uint2* staged    = (uint2*)(csr_val + NNZ);  // 12.8 MB

    // counts, cursor, needed, bcur contiguous -> one memset
    hipMemsetAsync(counts, 0, ((size_t)3 * N_NODE + 2048) * sizeof(int), stream);

    // ---- build CSR (two-pass bucketed scatter, L2-resident writes) ----
    csr_count<<<(NNZ + 255) / 256, 256, 0, stream>>>(adj_rows, counts);
    csr_scan1<<<SCAN_NBLK, 256, 0, stream>>>(counts, row_start, blk_sums);
    csr_scan2<<<1, 128, 0, stream>>>(blk_sums, blk_off);
    csr_scan3<<<SCAN_NBLK, 256, 0, stream>>>(row_start, blk_off);
    bucket_scatter<<<(NNZ + 255) / 256, 256, 0, stream>>>(adj_rows, adj_cols, adj_vals,
                                                          row_start, bcur, staged);
    csr_scatter2<<<NBUCK, 256, 0, stream>>>(staged, row_start, cursor, csr_col, csr_val);
    mark_needed<<<(NROWS + 255) / 256, 256, 0, stream>>>(session_item, needed);

    // ---- hyperconv: layer1 all rows, layer2 only rows attention reads ----
    const int spmm_grid = (N_NODE + 3) / 4;
    spmm_csr<<<spmm_grid, 256, 0, stream>>>(embedding, csr_col, csr_val, row_start,
                                            counts, needed, 0, emb1);
    spmm_csr<<<spmm_grid, 256, 0, stream>>>(emb1, csr_col, csr_val, row_start,
                                            counts, needed, 1, emb2);

    // ---- attention ----
    gather_project<<<NROWS / GP_ROWS, 256, 0, stream>>>(embedding, emb1, emb2,
                                                        session_item, W_q, W_k,
                                                        seqws, Qws, Kws);
    attn_score_pool<<<BATCH, 256, 0, stream>>>(Qws, Kws, seqws, session_len, mask,
                                               seqh, acc2);

    // ---- session graph ----
    gemm_DA<<<dim3(16, 16), 256, 0, stream>>>(D, A, DAb);
    sess_linear<<<BATCH, 128, 0, stream>>>(seqh, w_sess + 0 * EMB * EMB, tbuf);
    sess_prop  <<<BATCH, 128, 0, stream>>>(DAb, tbuf, sbuf, acc2, out, 0);
    sess_linear<<<BATCH, 128, 0, stream>>>(sbuf, w_sess + 1 * EMB * EMB, tbuf);
    sess_prop  <<<BATCH, 128, 0, stream>>>(DAb, tbuf, sbuf, acc2, out, 1);
}

// Round 5
// 599.638 us; speedup vs baseline: 1.2823x; 1.2823x over previous
//
#include <hip/hip_runtime.h>

#define N_NODE 100000
#define EMB 112
#define BATCH 512
#define SEQL 50
#define NNZ 1600000
#define NROWS (BATCH * SEQL)          // 25600 flattened session slots

#define SCAN_CHUNK 1024
#define SCAN_NBLK ((N_NODE + SCAN_CHUNK - 1) / SCAN_CHUNK)   // 98

#define NPASS 4
#define REGION ((NNZ + NPASS - 1) / NPASS)   // 400000 edges per dest region

__device__ __forceinline__ float bf2f(unsigned short u) {
    return __uint_as_float((unsigned)u << 16);
}
__device__ __forceinline__ unsigned short f2bf(float f) {
    unsigned u = __float_as_uint(f);
    return (unsigned short)((u + 0x7FFF + ((u >> 16) & 1)) >> 16);   // RNE
}

// ---------------- fp32 -> bf16 table copy ----------------------------------
__global__ __launch_bounds__(256) void to_bf16(
    const float* __restrict__ in, unsigned short* __restrict__ out)
{
    int i = blockIdx.x * 256 + threadIdx.x;          // one float4 -> ushort4
    const int n4 = N_NODE * EMB / 4;
    if (i >= n4) return;
    float4 v = ((const float4*)in)[i];
    ushort4 o;
    o.x = f2bf(v.x); o.y = f2bf(v.y); o.z = f2bf(v.z); o.w = f2bf(v.w);
    ((ushort4*)out)[i] = o;
}

// ---------------- CSR build ------------------------------------------------
__global__ __launch_bounds__(256) void csr_count(
    const int* __restrict__ rows, int* __restrict__ counts)
{
    int e = blockIdx.x * 256 + threadIdx.x;
    if (e < NNZ) atomicAdd(&counts[rows[e]], 1);
}

__global__ __launch_bounds__(256) void csr_scan1(
    const int* __restrict__ counts, int* __restrict__ row_start,
    int* __restrict__ blk_sums)
{
    __shared__ int lsum[256];
    const int tid = threadIdx.x;
    const int base = blockIdx.x * SCAN_CHUNK + tid * 4;
    int local[4], s = 0;
    for (int j = 0; j < 4; ++j) {
        int idx = base + j;
        int v = (idx < N_NODE) ? counts[idx] : 0;
        local[j] = s;
        s += v;
    }
    lsum[tid] = s;
    __syncthreads();
    for (int off = 1; off < 256; off <<= 1) {
        int t = (tid >= off) ? lsum[tid - off] : 0;
        __syncthreads();
        lsum[tid] += t;
        __syncthreads();
    }
    int thread_excl = lsum[tid] - s;
    for (int j = 0; j < 4; ++j) {
        int idx = base + j;
        if (idx < N_NODE) row_start[idx] = thread_excl + local[j];
    }
    if (tid == 255) blk_sums[blockIdx.x] = lsum[255];
}

__global__ __launch_bounds__(128) void csr_scan2(
    const int* __restrict__ blk_sums, int* __restrict__ blk_off)
{
    __shared__ int s[128];
    const int tid = threadIdx.x;
    int v = (tid < SCAN_NBLK) ? blk_sums[tid] : 0;
    s[tid] = v;
    __syncthreads();
    for (int off = 1; off < 128; off <<= 1) {
        int t = (tid >= off) ? s[tid - off] : 0;
        __syncthreads();
        s[tid] += t;
        __syncthreads();
    }
    if (tid < SCAN_NBLK) blk_off[tid] = s[tid] - v;
}

__global__ __launch_bounds__(256) void csr_scan3(
    int* __restrict__ row_start, const int* __restrict__ blk_off)
{
    int idx = blockIdx.x * SCAN_CHUNK + threadIdx.x * 4;
    int off = blk_off[blockIdx.x];
    for (int j = 0; j < 4; ++j)
        if (idx + j < N_NODE) row_start[idx + j] += off;
}

// ---- scatter, one dest region per launch (writes stay L2-resident) --------
__global__ __launch_bounds__(256) void csr_scatter_pass(
    const int* __restrict__ rows, const int* __restrict__ cols,
    const float* __restrict__ vals, const int* __restrict__ row_start,
    int* __restrict__ cursor, int2* __restrict__ csr_cv, int pass)
{
    int e = blockIdx.x * 256 + threadIdx.x;
    if (e >= NNZ) return;
    int r = rows[e];
    int base = row_start[r];
    if (base / REGION != pass) return;   // row's whole range handled in one pass
    int slot = base + atomicAdd(&cursor[r], 1);
    int2 cv;
    cv.x = cols[e];
    cv.y = __float_as_int(vals[e]);
    csr_cv[slot] = cv;
}

// mark rows of the embedding table that attention will actually read
__global__ __launch_bounds__(256) void mark_needed(
    const int* __restrict__ items, int* __restrict__ needed)
{
    int i = blockIdx.x * 256 + threadIdx.x;
    if (i >= NROWS) return;
    int g = items[i];
    if (g > 0) needed[g - 1] = 1;     // benign races, all write 1
}

// ---------------- HyperConv layer: bf16 gather, 2 rows per wave ------------
// half-wave (32 lanes) per row; lanes 0..27 own float4 feature chunks.
__global__ __launch_bounds__(256) void spmm_bf16(
    const unsigned short* __restrict__ src, const int2* __restrict__ csr_cv,
    const int* __restrict__ row_start, const int* __restrict__ counts,
    const int* __restrict__ needed, int use_needed,
    unsigned short* __restrict__ dst)
{
    const int lane = threadIdx.x & 63;
    const int wave = threadIdx.x >> 6;
    const int half = lane >> 5;
    const int hl = lane & 31;
    const int row = blockIdx.x * 8 + wave * 2 + half;   // grid covers exactly N_NODE
    const bool act = hl < 28;
    const int d0 = hl * 4;

    const bool skip = use_needed && (needed[row] == 0);
    int n = skip ? 0 : counts[row];
    const int beg = row_start[row];

    float a0 = 0.f, a1 = 0.f, a2 = 0.f, a3 = 0.f;
    int i = 0;
    for (; i + 8 <= n; i += 8) {
        #pragma unroll
        for (int j = 0; j < 8; ++j) {
            int2 cv = csr_cv[beg + i + j];
            float v = __int_as_float(cv.y);
            if (act) {
                ushort4 u = *(const ushort4*)(src + (size_t)cv.x * EMB + d0);
                a0 += v * bf2f(u.x);
                a1 += v * bf2f(u.y);
                a2 += v * bf2f(u.z);
                a3 += v * bf2f(u.w);
            }
        }
    }
    for (; i < n; ++i) {
        int2 cv = csr_cv[beg + i];
        float v = __int_as_float(cv.y);
        if (act) {
            ushort4 u = *(const ushort4*)(src + (size_t)cv.x * EMB + d0);
            a0 += v * bf2f(u.x);
            a1 += v * bf2f(u.y);
            a2 += v * bf2f(u.z);
            a3 += v * bf2f(u.w);
        }
    }
    if (act && !skip) {
        ushort4 o;
        o.x = f2bf(a0); o.y = f2bf(a1); o.z = f2bf(a2); o.w = f2bf(a3);
        *(ushort4*)(dst + (size_t)row * EMB + d0) = o;
    }
}

// ---------------- gather + Q/K projection (register-tiled) -----------------
#define GP_ROWS 32
#define SEQ_PAD 116
__global__ __launch_bounds__(256) void gather_project(
    const float* __restrict__ emb0,
    const unsigned short* __restrict__ e1b, const unsigned short* __restrict__ e2b,
    const int* __restrict__ items,
    const float* __restrict__ Wq, const float* __restrict__ Wk,
    float* __restrict__ seqws, float* __restrict__ Qws, float* __restrict__ Kws)
{
    __shared__ float s_seq[GP_ROWS][SEQ_PAD];
    const int t = threadIdx.x;
    const int R0 = blockIdx.x * GP_ROWS;

    for (int idx = t; idx < GP_ROWS * EMB; idx += 256) {
        int r = idx / EMB, d = idx - r * EMB;
        int g = items[R0 + r];
        float v = 0.f;
        if (g > 0) {
            size_t off = (size_t)(g - 1) * EMB + d;
            v = (emb0[off] + bf2f(e1b[off]) + bf2f(e2b[off])) * (1.f / 3.f);
        }
        s_seq[r][d] = v;
        seqws[(size_t)(R0 + r) * EMB + d] = v;
    }
    __syncthreads();

    if (t >= 224) return;
    const int rg = t / 28;
    const int e0 = (t % 28) * 4;

    float accq[4][4] = {{0.f}}, acck[4][4] = {{0.f}};
    for (int d4 = 0; d4 < 28; ++d4) {
        float sa[4][4];
        #pragma unroll
        for (int rr = 0; rr < 4; ++rr) {
            float4 v = *(const float4*)&s_seq[rg * 4 + rr][d4 * 4];
            sa[rr][0] = v.x; sa[rr][1] = v.y; sa[rr][2] = v.z; sa[rr][3] = v.w;
        }
        #pragma unroll
        for (int j = 0; j < 4; ++j) {
            const int d = d4 * 4 + j;
            float4 wq = *(const float4*)&Wq[d * EMB + e0];
            float4 wk = *(const float4*)&Wk[d * EMB + e0];
            #pragma unroll
            for (int rr = 0; rr < 4; ++rr) {
                float s = sa[rr][j];
                accq[rr][0] += s * wq.x; accq[rr][1] += s * wq.y;
                accq[rr][2] += s * wq.z; accq[rr][3] += s * wq.w;
                acck[rr][0] += s * wk.x; acck[rr][1] += s * wk.y;
                acck[rr][2] += s * wk.z; acck[rr][3] += s * wk.w;
            }
        }
    }
    #pragma unroll
    for (int rr = 0; rr < 4; ++rr) {
        size_t o = (size_t)(R0 + rg * 4 + rr) * EMB + e0;
        float4 q, k;
        q.x = 1.f / (1.f + __expf(-accq[rr][0]));
        q.y = 1.f / (1.f + __expf(-accq[rr][1]));
        q.z = 1.f / (1.f + __expf(-accq[rr][2]));
        q.w = 1.f / (1.f + __expf(-accq[rr][3]));
        k.x = 1.f / (1.f + __expf(-acck[rr][0]));
        k.y = 1.f / (1.f + __expf(-acck[rr][1]));
        k.z = 1.f / (1.f + __expf(-acck[rr][2]));
        k.w = 1.f / (1.f + __expf(-acck[rr][3]));
        *(float4*)&Qws[o] = q;
        *(float4*)&Kws[o] = k;
    }
}

// ---------------- scores + softmax + pooling (no LDS atomics) --------------
__global__ __launch_bounds__(256) void attn_score_pool(
    const float* __restrict__ Qws, const float* __restrict__ Kws,
    const float* __restrict__ seqws,
    const int* __restrict__ session_len, const float* __restrict__ mask,
    float* __restrict__ seq_h, float* __restrict__ acc2)
{
    __shared__ float sQ[SEQL][SEQ_PAD];
    __shared__ float sK[SEQL][SEQ_PAD];
    __shared__ float s_part[SEQL][4];
    __shared__ float s_mask[SEQL];
    __shared__ float s_beta[SEQL];

    const int b = blockIdx.x;
    const int t = threadIdx.x;

    for (int idx = t; idx < SEQL * (EMB / 4); idx += 256) {
        int l = idx / (EMB / 4), d4 = idx - l * (EMB / 4);
        *(float4*)&sQ[l][d4 * 4] = *(const float4*)&Qws[((size_t)b * SEQL + l) * EMB + d4 * 4];
        *(float4*)&sK[l][d4 * 4] = *(const float4*)&Kws[((size_t)b * SEQL + l) * EMB + d4 * 4];
    }
    if (t < SEQL) s_mask[t] = mask[b * SEQL + t];
    __syncthreads();

    const float inv_sqrt_d = rsqrtf((float)EMB);
    if (t < 200) {
        const int l = t >> 2;
        const int m0 = t & 3;
        float partial = 0.f;
        if (s_mask[l] != 0.f) {
            for (int m = m0; m < SEQL; m += 4) {
                if (m == l || s_mask[m] == 0.f) continue;
                float dot = 0.f;
                for (int d4 = 0; d4 < EMB / 4; ++d4) {
                    float4 a = *(const float4*)&sQ[l][d4 * 4];
                    float4 c = *(const float4*)&sK[m][d4 * 4];
                    dot += a.x * c.x + a.y * c.y + a.z * c.z + a.w * c.w;
                }
                partial += inv_sqrt_d / (1.f + __expf(-dot));
            }
        }
        s_part[l][m0] = partial;
    }
    __syncthreads();

    if (t < 64) {
        float slen = (float)session_len[b];
        float a = -1e30f;
        if (t < SEQL && s_mask[t] > 0.f)
            a = (s_part[t][0] + s_part[t][1] + s_part[t][2] + s_part[t][3]) / slen;
        float mx = a;
        for (int o = 32; o > 0; o >>= 1) mx = fmaxf(mx, __shfl_xor(mx, o));
        float ex = __expf(a - mx);
        float sm = ex;
        for (int o = 32; o > 0; o >>= 1) sm += __shfl_xor(sm, o);
        if (t < SEQL) s_beta[t] = ex / sm;
    }
    __syncthreads();

    if (t < EMB) {
        float h = 0.f;
        for (int l = 0; l < SEQL; ++l)
            h += s_beta[l] * seqws[((size_t)b * SEQL + l) * EMB + t];
        seq_h[b * EMB + t] = h;
        acc2[b * EMB + t] = h;
    }
}

// ---------------- DA = D @ A  (32x32 LDS-tiled) ----------------------------
__global__ __launch_bounds__(256) void gemm_DA(
    const float* __restrict__ D, const float* __restrict__ A,
    float* __restrict__ DA)
{
    __shared__ float sD[32][33];
    __shared__ float sA[32][33];
    const int tx = threadIdx.x & 15;
    const int ty = threadIdx.x >> 4;
    const int i0 = blockIdx.y * 32;
    const int j0 = blockIdx.x * 32;
    float a00 = 0.f, a01 = 0.f, a10 = 0.f, a11 = 0.f;
    for (int k0 = 0; k0 < BATCH; k0 += 32) {
        for (int idx = threadIdx.x; idx < 1024; idx += 256) {
            int r = idx >> 5, c = idx & 31;
            sD[r][c] = D[(i0 + r) * BATCH + k0 + c];
            sA[r][c] = A[(k0 + r) * BATCH + j0 + c];
        }
        __syncthreads();
        #pragma unroll 8
        for (int kk = 0; kk < 32; ++kk) {
            float d0 = sD[2 * ty][kk], d1 = sD[2 * ty + 1][kk];
            float b0 = sA[kk][2 * tx], b1 = sA[kk][2 * tx + 1];
            a00 += d0 * b0; a01 += d0 * b1;
            a10 += d1 * b0; a11 += d1 * b1;
        }
        __syncthreads();
    }
    DA[(i0 + 2 * ty) * BATCH + j0 + 2 * tx] = a00;
    DA[(i0 + 2 * ty) * BATCH + j0 + 2 * tx + 1] = a01;
    DA[(i0 + 2 * ty + 1) * BATCH + j0 + 2 * tx] = a10;
    DA[(i0 + 2 * ty + 1) * BATCH + j0 + 2 * tx + 1] = a11;
}

// ---------------- t = s @ W^T ----------------------------------------------
__global__ __launch_bounds__(128) void sess_linear(
    const float* __restrict__ s, const float* __restrict__ W,
    float* __restrict__ t)
{
    __shared__ float s_row[EMB];
    int b = blockIdx.x;
    int e = threadIdx.x;
    if (e < EMB) s_row[e] = s[b * EMB + e];
    __syncthreads();
    if (e >= EMB) return;
    float acc = 0.f;
    for (int d = 0; d < EMB; ++d) acc += s_row[d] * W[e * EMB + d];
    t[b * EMB + e] = acc;
}

// ---------------- s = DA @ t; acc2 += s/||s||; last: out = acc2/3 ----------
__global__ __launch_bounds__(128) void sess_prop(
    const float* __restrict__ DA, const float* __restrict__ t,
    float* __restrict__ s_out, float* __restrict__ acc2,
    float* __restrict__ out, int is_last)
{
    __shared__ float s_da[BATCH];
    __shared__ float s_sq[128];
    int b = blockIdx.x;
    int e = threadIdx.x;
    for (int k = e; k < BATCH; k += 128) s_da[k] = DA[b * BATCH + k];
    __syncthreads();

    float v = 0.f;
    if (e < EMB) {
        for (int k = 0; k < BATCH; ++k) v += s_da[k] * t[k * EMB + e];
    }
    s_sq[e] = (e < EMB) ? v * v : 0.f;
    __syncthreads();
    for (int off = 64; off > 0; off >>= 1) {
        if (e < off) s_sq[e] += s_sq[e + off];
        __syncthreads();
    }
    float nrm = fmaxf(sqrtf(s_sq[0]), 1e-12f);
    if (e < EMB) {
        float a = acc2[b * EMB + e] + v / nrm;
        acc2[b * EMB + e] = a;
        s_out[b * EMB + e] = v;
        if (is_last) out[b * EMB + e] = a * (1.f / 3.f);
    }
}

extern "C" void kernel_launch(void* const* d_in, const int* in_sizes, int n_in,
                              void* d_out, int out_size, void* d_ws, size_t ws_size,
                              hipStream_t stream)
{
    (void)in_sizes; (void)n_in; (void)out_size; (void)ws_size;

    const float* embedding    = (const float*)d_in[0];
    const float* adj_vals     = (const float*)d_in[1];
    const float* W_q          = (const float*)d_in[2];
    const float* W_k          = (const float*)d_in[3];
    const float* w_sess       = (const float*)d_in[4];
    const float* D            = (const float*)d_in[5];
    const float* A            = (const float*)d_in[6];
    const int*   adj_rows     = (const int*)d_in[7];
    const int*   adj_cols     = (const int*)d_in[8];
    const int*   session_item = (const int*)d_in[9];
    const int*   session_len  = (const int*)d_in[10];
    const float* mask         = (const float*)d_in[11];
    float* out = (float*)d_out;

    // ---- workspace layout ----
    // bf16 tables first (8B-aligned at base)
    unsigned short* ebf0 = (unsigned short*)d_ws;                 // 11.2M ushort
    unsigned short* ebf1 = ebf0 + (size_t)N_NODE * EMB;
    unsigned short* ebf2 = ebf1 + (size_t)N_NODE * EMB;
    float* DAb       = (float*)(ebf2 + (size_t)N_NODE * EMB);     // 33.6M ushort = 67.2MB, 8B-aligned
    float* seqh      = DAb  + (size_t)BATCH * BATCH;
    float* acc2      = seqh + (size_t)BATCH * EMB;
    float* tbuf      = acc2 + (size_t)BATCH * EMB;
    float* sbuf      = tbuf + (size_t)BATCH * EMB;
    float* seqws     = sbuf + (size_t)BATCH * EMB;
    float* Qws       = seqws + (size_t)NROWS * EMB;
    float* Kws       = Qws   + (size_t)NROWS * EMB;
    int*   counts    = (int*)(Kws + (size_t)NROWS * EMB);
    int*   cursor    = counts + N_NODE;
    int*   needed    = cursor + N_NODE;
    int*   row_start = needed + N_NODE;
    int*   blk_sums  = row_start + N_NODE;
    int*   blk_off   = blk_sums + 128;
    int2*  csr_cv    = (int2*)(blk_off + 128 + 2);                // 12.8 MB (8B-aligned: offset even ints)

    // counts, cursor, needed contiguous -> one memset
    hipMemsetAsync(counts, 0, (size_t)3 * N_NODE * sizeof(int), stream);

    // ---- bf16 copy of the embedding table (L2-resident gather source) ----
    to_bf16<<<(N_NODE * EMB / 4 + 255) / 256, 256, 0, stream>>>(embedding, ebf0);

    // ---- build CSR ----
    csr_count<<<(NNZ + 255) / 256, 256, 0, stream>>>(adj_rows, counts);
    csr_scan1<<<SCAN_NBLK, 256, 0, stream>>>(counts, row_start, blk_sums);
    csr_scan2<<<1, 128, 0, stream>>>(blk_sums, blk_off);
    csr_scan3<<<SCAN_NBLK, 256, 0, stream>>>(row_start, blk_off);
    for (int p = 0; p < NPASS; ++p)
        csr_scatter_pass<<<(NNZ + 255) / 256, 256, 0, stream>>>(
            adj_rows, adj_cols, adj_vals, row_start, cursor, csr_cv, p);
    mark_needed<<<(NROWS + 255) / 256, 256, 0, stream>>>(session_item, needed);

    // ---- hyperconv: layer1 all rows, layer2 only rows attention reads ----
    const int spmm_grid = N_NODE / 8;   // 12500, exact
    spmm_bf16<<<spmm_grid, 256, 0, stream>>>(ebf0, csr_cv, row_start, counts,
                                             needed, 0, ebf1);
    spmm_bf16<<<spmm_grid, 256, 0, stream>>>(ebf1, csr_cv, row_start, counts,
                                             needed, 1, ebf2);

    // ---- attention ----
    gather_project<<<NROWS / GP_ROWS, 256, 0, stream>>>(embedding, ebf1, ebf2,
                                                        session_item, W_q, W_k,
                                                        seqws, Qws, Kws);
    attn_score_pool<<<BATCH, 256, 0, stream>>>(Qws, Kws, seqws, session_len, mask,
                                               seqh, acc2);

    // ---- session graph ----
    gemm_DA<<<dim3(16, 16), 256, 0, stream>>>(D, A, DAb);
    sess_linear<<<BATCH, 128, 0, stream>>>(seqh, w_sess + 0 * EMB * EMB, tbuf);
    sess_prop  <<<BATCH, 128, 0, stream>>>(DAb, tbuf, sbuf, acc2, out, 0);
    sess_linear<<<BATCH, 128, 0, stream>>>(sbuf, w_sess + 1 * EMB * EMB, tbuf);
    sess_prop  <<<BATCH, 128, 0, stream>>>(DAb, tbuf, sbuf, acc2, out, 1);
}

// Round 6
// 597.685 us; speedup vs baseline: 1.2865x; 1.0033x over previous
//
#include <hip/hip_runtime.h>

#define N_NODE 100000
#define EMB 112
#define BATCH 512
#define SEQL 50
#define NNZ 1600000
#define NROWS (BATCH * SEQL)          // 25600 flattened session slots
#define NNZ_PAD (NNZ + 8 * N_NODE)    // worst-case padded edge count

#define SCAN_CHUNK 1024
#define SCAN_NBLK ((N_NODE + SCAN_CHUNK - 1) / SCAN_CHUNK)   // 98

__device__ __forceinline__ float bf2f(unsigned short u) {
    return __uint_as_float((unsigned)u << 16);
}
__device__ __forceinline__ unsigned short f2bf(float f) {
    unsigned u = __float_as_uint(f);
    return (unsigned short)((u + 0x7FFF + ((u >> 16) & 1)) >> 16);   // RNE
}

// ---------------- fp32 -> bf16 table copy ----------------------------------
__global__ __launch_bounds__(256) void to_bf16(
    const float* __restrict__ in, unsigned short* __restrict__ out)
{
    int i = blockIdx.x * 256 + threadIdx.x;          // one float4 -> ushort4
    const int n4 = N_NODE * EMB / 4;
    if (i >= n4) return;
    float4 v = ((const float4*)in)[i];
    ushort4 o;
    o.x = f2bf(v.x); o.y = f2bf(v.y); o.z = f2bf(v.z); o.w = f2bf(v.w);
    ((ushort4*)out)[i] = o;
}

// ---------------- CSR build ------------------------------------------------
__global__ __launch_bounds__(256) void csr_count(
    const int* __restrict__ rows, int* __restrict__ counts)
{
    int e = blockIdx.x * 256 + threadIdx.x;
    if (e < NNZ) atomicAdd(&counts[rows[e]], 1);
}

// scan over counts PADDED to a multiple of 8 -> padded row_start
__global__ __launch_bounds__(256) void csr_scan1(
    const int* __restrict__ counts, int* __restrict__ row_start,
    int* __restrict__ blk_sums)
{
    __shared__ int lsum[256];
    const int tid = threadIdx.x;
    const int base = blockIdx.x * SCAN_CHUNK + tid * 4;
    int local[4], s = 0;
    for (int j = 0; j < 4; ++j) {
        int idx = base + j;
        int v = (idx < N_NODE) ? ((counts[idx] + 7) & ~7) : 0;   // pad to x8
        local[j] = s;
        s += v;
    }
    lsum[tid] = s;
    __syncthreads();
    for (int off = 1; off < 256; off <<= 1) {
        int t = (tid >= off) ? lsum[tid - off] : 0;
        __syncthreads();
        lsum[tid] += t;
        __syncthreads();
    }
    int thread_excl = lsum[tid] - s;
    for (int j = 0; j < 4; ++j) {
        int idx = base + j;
        if (idx < N_NODE) row_start[idx] = thread_excl + local[j];
    }
    if (tid == 255) blk_sums[blockIdx.x] = lsum[255];
}

__global__ __launch_bounds__(128) void csr_scan2(
    const int* __restrict__ blk_sums, int* __restrict__ blk_off)
{
    __shared__ int s[128];
    const int tid = threadIdx.x;
    int v = (tid < SCAN_NBLK) ? blk_sums[tid] : 0;
    s[tid] = v;
    __syncthreads();
    for (int off = 1; off < 128; off <<= 1) {
        int t = (tid >= off) ? s[tid - off] : 0;
        __syncthreads();
        s[tid] += t;
        __syncthreads();
    }
    if (tid < SCAN_NBLK) blk_off[tid] = s[tid] - v;
}

__global__ __launch_bounds__(256) void csr_scan3(
    int* __restrict__ row_start, const int* __restrict__ blk_off)
{
    int idx = blockIdx.x * SCAN_CHUNK + threadIdx.x * 4;
    int off = blk_off[blockIdx.x];
    for (int j = 0; j < 4; ++j)
        if (idx + j < N_NODE) row_start[idx + j] += off;
}

// single-pass scatter, one packed 8B store per edge (R3 structure + packing)
__global__ __launch_bounds__(256) void csr_scatter_packed(
    const int* __restrict__ rows, const int* __restrict__ cols,
    const float* __restrict__ vals, const int* __restrict__ row_start,
    int* __restrict__ cursor, int2* __restrict__ csr_cv)
{
    int e = blockIdx.x * 256 + threadIdx.x;
    if (e >= NNZ) return;
    int r = rows[e];
    int slot = row_start[r] + atomicAdd(&cursor[r], 1);
    int2 cv;
    cv.x = cols[e];
    cv.y = __float_as_int(vals[e]);
    csr_cv[slot] = cv;
}

// mark rows of the embedding table that attention will actually read
__global__ __launch_bounds__(256) void mark_needed(
    const int* __restrict__ items, int* __restrict__ needed)
{
    int i = blockIdx.x * 256 + threadIdx.x;
    if (i >= NROWS) return;
    int g = items[i];
    if (g > 0) needed[g - 1] = 1;     // benign races, all write 1
}

// ---------------- HyperConv layer: bf16 gather, padded rows, no remainder --
// half-wave (32 lanes) per row; lanes 0..27 own ushort4 feature chunks.
// Row edge count padded to x8; pad edges are (col=0, val=0) -> contribute 0.
__global__ __launch_bounds__(256) void spmm_bf16(
    const unsigned short* __restrict__ src, const int2* __restrict__ csr_cv,
    const int* __restrict__ row_start, const int* __restrict__ counts,
    const int* __restrict__ needed, int use_needed,
    unsigned short* __restrict__ dst)
{
    const int lane = threadIdx.x & 63;
    const int wave = threadIdx.x >> 6;
    const int half = lane >> 5;
    const int hl = lane & 31;
    const int row = blockIdx.x * 8 + wave * 2 + half;   // grid covers exactly N_NODE
    const bool act = hl < 28;
    const int d0 = hl * 4;

    const bool skip = use_needed && (needed[row] == 0);
    const int n_pad = skip ? 0 : ((counts[row] + 7) & ~7);
    const int beg = row_start[row];

    float a0 = 0.f, a1 = 0.f, a2 = 0.f, a3 = 0.f;
    for (int i = 0; i < n_pad; i += 8) {
        #pragma unroll
        for (int j = 0; j < 8; ++j) {
            int2 cv = csr_cv[beg + i + j];
            float v = __int_as_float(cv.y);
            if (act) {
                ushort4 u = *(const ushort4*)(src + (size_t)cv.x * EMB + d0);
                a0 += v * bf2f(u.x);
                a1 += v * bf2f(u.y);
                a2 += v * bf2f(u.z);
                a3 += v * bf2f(u.w);
            }
        }
    }
    if (act && !skip) {
        ushort4 o;
        o.x = f2bf(a0); o.y = f2bf(a1); o.z = f2bf(a2); o.w = f2bf(a3);
        *(ushort4*)(dst + (size_t)row * EMB + d0) = o;
    }
}

// ---------------- gather + Q/K projection (register-tiled) -----------------
#define GP_ROWS 32
#define SEQ_PAD 116
__global__ __launch_bounds__(256) void gather_project(
    const float* __restrict__ emb0,
    const unsigned short* __restrict__ e1b, const unsigned short* __restrict__ e2b,
    const int* __restrict__ items,
    const float* __restrict__ Wq, const float* __restrict__ Wk,
    float* __restrict__ seqws, float* __restrict__ Qws, float* __restrict__ Kws)
{
    __shared__ float s_seq[GP_ROWS][SEQ_PAD];
    const int t = threadIdx.x;
    const int R0 = blockIdx.x * GP_ROWS;

    for (int idx = t; idx < GP_ROWS * EMB; idx += 256) {
        int r = idx / EMB, d = idx - r * EMB;
        int g = items[R0 + r];
        float v = 0.f;
        if (g > 0) {
            size_t off = (size_t)(g - 1) * EMB + d;
            v = (emb0[off] + bf2f(e1b[off]) + bf2f(e2b[off])) * (1.f / 3.f);
        }
        s_seq[r][d] = v;
        seqws[(size_t)(R0 + r) * EMB + d] = v;
    }
    __syncthreads();

    if (t >= 224) return;
    const int rg = t / 28;
    const int e0 = (t % 28) * 4;

    float accq[4][4] = {{0.f}}, acck[4][4] = {{0.f}};
    for (int d4 = 0; d4 < 28; ++d4) {
        float sa[4][4];
        #pragma unroll
        for (int rr = 0; rr < 4; ++rr) {
            float4 v = *(const float4*)&s_seq[rg * 4 + rr][d4 * 4];
            sa[rr][0] = v.x; sa[rr][1] = v.y; sa[rr][2] = v.z; sa[rr][3] = v.w;
        }
        #pragma unroll
        for (int j = 0; j < 4; ++j) {
            const int d = d4 * 4 + j;
            float4 wq = *(const float4*)&Wq[d * EMB + e0];
            float4 wk = *(const float4*)&Wk[d * EMB + e0];
            #pragma unroll
            for (int rr = 0; rr < 4; ++rr) {
                float s = sa[rr][j];
                accq[rr][0] += s * wq.x; accq[rr][1] += s * wq.y;
                accq[rr][2] += s * wq.z; accq[rr][3] += s * wq.w;
                acck[rr][0] += s * wk.x; acck[rr][1] += s * wk.y;
                acck[rr][2] += s * wk.z; acck[rr][3] += s * wk.w;
            }
        }
    }
    #pragma unroll
    for (int rr = 0; rr < 4; ++rr) {
        size_t o = (size_t)(R0 + rg * 4 + rr) * EMB + e0;
        float4 q, k;
        q.x = 1.f / (1.f + __expf(-accq[rr][0]));
        q.y = 1.f / (1.f + __expf(-accq[rr][1]));
        q.z = 1.f / (1.f + __expf(-accq[rr][2]));
        q.w = 1.f / (1.f + __expf(-accq[rr][3]));
        k.x = 1.f / (1.f + __expf(-acck[rr][0]));
        k.y = 1.f / (1.f + __expf(-acck[rr][1]));
        k.z = 1.f / (1.f + __expf(-acck[rr][2]));
        k.w = 1.f / (1.f + __expf(-acck[rr][3]));
        *(float4*)&Qws[o] = q;
        *(float4*)&Kws[o] = k;
    }
}

// ---------------- scores + softmax + pooling (no LDS atomics) --------------
__global__ __launch_bounds__(256) void attn_score_pool(
    const float* __restrict__ Qws, const float* __restrict__ Kws,
    const float* __restrict__ seqws,
    const int* __restrict__ session_len, const float* __restrict__ mask,
    float* __restrict__ seq_h, float* __restrict__ acc2)
{
    __shared__ float sQ[SEQL][SEQ_PAD];
    __shared__ float sK[SEQL][SEQ_PAD];
    __shared__ float s_part[SEQL][4];
    __shared__ float s_mask[SEQL];
    __shared__ float s_beta[SEQL];

    const int b = blockIdx.x;
    const int t = threadIdx.x;

    for (int idx = t; idx < SEQL * (EMB / 4); idx += 256) {
        int l = idx / (EMB / 4), d4 = idx - l * (EMB / 4);
        *(float4*)&sQ[l][d4 * 4] = *(const float4*)&Qws[((size_t)b * SEQL + l) * EMB + d4 * 4];
        *(float4*)&sK[l][d4 * 4] = *(const float4*)&Kws[((size_t)b * SEQL + l) * EMB + d4 * 4];
    }
    if (t < SEQL) s_mask[t] = mask[b * SEQL + t];
    __syncthreads();

    const float inv_sqrt_d = rsqrtf((float)EMB);
    if (t < 200) {
        const int l = t >> 2;
        const int m0 = t & 3;
        float partial = 0.f;
        if (s_mask[l] != 0.f) {
            for (int m = m0; m < SEQL; m += 4) {
                if (m == l || s_mask[m] == 0.f) continue;
                float dot = 0.f;
                for (int d4 = 0; d4 < EMB / 4; ++d4) {
                    float4 a = *(const float4*)&sQ[l][d4 * 4];
                    float4 c = *(const float4*)&sK[m][d4 * 4];
                    dot += a.x * c.x + a.y * c.y + a.z * c.z + a.w * c.w;
                }
                partial += inv_sqrt_d / (1.f + __expf(-dot));
            }
        }
        s_part[l][m0] = partial;
    }
    __syncthreads();

    if (t < 64) {
        float slen = (float)session_len[b];
        float a = -1e30f;
        if (t < SEQL && s_mask[t] > 0.f)
            a = (s_part[t][0] + s_part[t][1] + s_part[t][2] + s_part[t][3]) / slen;
        float mx = a;
        for (int o = 32; o > 0; o >>= 1) mx = fmaxf(mx, __shfl_xor(mx, o));
        float ex = __expf(a - mx);
        float sm = ex;
        for (int o = 32; o > 0; o >>= 1) sm += __shfl_xor(sm, o);
        if (t < SEQL) s_beta[t] = ex / sm;
    }
    __syncthreads();

    if (t < EMB) {
        float h = 0.f;
        for (int l = 0; l < SEQL; ++l)
            h += s_beta[l] * seqws[((size_t)b * SEQL + l) * EMB + t];
        seq_h[b * EMB + t] = h;
        acc2[b * EMB + t] = h;
    }
}

// ---------------- DA = D @ A  (32x32 LDS-tiled) ----------------------------
__global__ __launch_bounds__(256) void gemm_DA(
    const float* __restrict__ D, const float* __restrict__ A,
    float* __restrict__ DA)
{
    __shared__ float sD[32][33];
    __shared__ float sA[32][33];
    const int tx = threadIdx.x & 15;
    const int ty = threadIdx.x >> 4;
    const int i0 = blockIdx.y * 32;
    const int j0 = blockIdx.x * 32;
    float a00 = 0.f, a01 = 0.f, a10 = 0.f, a11 = 0.f;
    for (int k0 = 0; k0 < BATCH; k0 += 32) {
        for (int idx = threadIdx.x; idx < 1024; idx += 256) {
            int r = idx >> 5, c = idx & 31;
            sD[r][c] = D[(i0 + r) * BATCH + k0 + c];
            sA[r][c] = A[(k0 + r) * BATCH + j0 + c];
        }
        __syncthreads();
        #pragma unroll 8
        for (int kk = 0; kk < 32; ++kk) {
            float d0 = sD[2 * ty][kk], d1 = sD[2 * ty + 1][kk];
            float b0 = sA[kk][2 * tx], b1 = sA[kk][2 * tx + 1];
            a00 += d0 * b0; a01 += d0 * b1;
            a10 += d1 * b0; a11 += d1 * b1;
        }
        __syncthreads();
    }
    DA[(i0 + 2 * ty) * BATCH + j0 + 2 * tx] = a00;
    DA[(i0 + 2 * ty) * BATCH + j0 + 2 * tx + 1] = a01;
    DA[(i0 + 2 * ty + 1) * BATCH + j0 + 2 * tx] = a10;
    DA[(i0 + 2 * ty + 1) * BATCH + j0 + 2 * tx + 1] = a11;
}

// ---------------- t = s @ W^T ----------------------------------------------
__global__ __launch_bounds__(128) void sess_linear(
    const float* __restrict__ s, const float* __restrict__ W,
    float* __restrict__ t)
{
    __shared__ float s_row[EMB];
    int b = blockIdx.x;
    int e = threadIdx.x;
    if (e < EMB) s_row[e] = s[b * EMB + e];
    __syncthreads();
    if (e >= EMB) return;
    float acc = 0.f;
    for (int d = 0; d < EMB; ++d) acc += s_row[d] * W[e * EMB + d];
    t[b * EMB + e] = acc;
}

// ---------------- s = DA @ t; acc2 += s/||s||; last: out = acc2/3 ----------
__global__ __launch_bounds__(128) void sess_prop(
    const float* __restrict__ DA, const float* __restrict__ t,
    float* __restrict__ s_out, float* __restrict__ acc2,
    float* __restrict__ out, int is_last)
{
    __shared__ float s_da[BATCH];
    __shared__ float s_sq[128];
    int b = blockIdx.x;
    int e = threadIdx.x;
    for (int k = e; k < BATCH; k += 128) s_da[k] = DA[b * BATCH + k];
    __syncthreads();

    float v = 0.f;
    if (e < EMB) {
        for (int k = 0; k < BATCH; ++k) v += s_da[k] * t[k * EMB + e];
    }
    s_sq[e] = (e < EMB) ? v * v : 0.f;
    __syncthreads();
    for (int off = 64; off > 0; off >>= 1) {
        if (e < off) s_sq[e] += s_sq[e + off];
        __syncthreads();
    }
    float nrm = fmaxf(sqrtf(s_sq[0]), 1e-12f);
    if (e < EMB) {
        float a = acc2[b * EMB + e] + v / nrm;
        acc2[b * EMB + e] = a;
        s_out[b * EMB + e] = v;
        if (is_last) out[b * EMB + e] = a * (1.f / 3.f);
    }
}

extern "C" void kernel_launch(void* const* d_in, const int* in_sizes, int n_in,
                              void* d_out, int out_size, void* d_ws, size_t ws_size,
                              hipStream_t stream)
{
    (void)in_sizes; (void)n_in; (void)out_size; (void)ws_size;

    const float* embedding    = (const float*)d_in[0];
    const float* adj_vals     = (const float*)d_in[1];
    const float* W_q          = (const float*)d_in[2];
    const float* W_k          = (const float*)d_in[3];
    const float* w_sess       = (const float*)d_in[4];
    const float* D            = (const float*)d_in[5];
    const float* A            = (const float*)d_in[6];
    const int*   adj_rows     = (const int*)d_in[7];
    const int*   adj_cols     = (const int*)d_in[8];
    const int*   session_item = (const int*)d_in[9];
    const int*   session_len  = (const int*)d_in[10];
    const float* mask         = (const float*)d_in[11];
    float* out = (float*)d_out;

    // ---- workspace layout ----
    unsigned short* ebf0 = (unsigned short*)d_ws;                 // 11.2M ushort
    unsigned short* ebf1 = ebf0 + (size_t)N_NODE * EMB;
    unsigned short* ebf2 = ebf1 + (size_t)N_NODE * EMB;
    float* DAb       = (float*)(ebf2 + (size_t)N_NODE * EMB);     // 8B-aligned
    float* seqh      = DAb  + (size_t)BATCH * BATCH;
    float* acc2      = seqh + (size_t)BATCH * EMB;
    float* tbuf      = acc2 + (size_t)BATCH * EMB;
    float* sbuf      = tbuf + (size_t)BATCH * EMB;
    float* seqws     = sbuf + (size_t)BATCH * EMB;
    float* Qws       = seqws + (size_t)NROWS * EMB;
    float* Kws       = Qws   + (size_t)NROWS * EMB;
    int*   counts    = (int*)(Kws + (size_t)NROWS * EMB);
    int*   cursor    = counts + N_NODE;
    int*   needed    = cursor + N_NODE;
    int*   row_start = needed + N_NODE;
    int*   blk_sums  = row_start + N_NODE;
    int*   blk_off   = blk_sums + 128;
    int2*  csr_cv    = (int2*)(blk_off + 128 + 2);                // NNZ_PAD int2, 8B-aligned

    // counts, cursor, needed contiguous -> one memset; csr_cv zeroed for pads
    hipMemsetAsync(counts, 0, (size_t)3 * N_NODE * sizeof(int), stream);
    hipMemsetAsync(csr_cv, 0, (size_t)NNZ_PAD * sizeof(int2), stream);

    // ---- bf16 copy of the embedding table (L2/L3-resident gather source) ----
    to_bf16<<<(N_NODE * EMB / 4 + 255) / 256, 256, 0, stream>>>(embedding, ebf0);

    // ---- build padded CSR ----
    csr_count<<<(NNZ + 255) / 256, 256, 0, stream>>>(adj_rows, counts);
    csr_scan1<<<SCAN_NBLK, 256, 0, stream>>>(counts, row_start, blk_sums);
    csr_scan2<<<1, 128, 0, stream>>>(blk_sums, blk_off);
    csr_scan3<<<SCAN_NBLK, 256, 0, stream>>>(row_start, blk_off);
    csr_scatter_packed<<<(NNZ + 255) / 256, 256, 0, stream>>>(
        adj_rows, adj_cols, adj_vals, row_start, cursor, csr_cv);
    mark_needed<<<(NROWS + 255) / 256, 256, 0, stream>>>(session_item, needed);

    // ---- hyperconv: layer1 all rows, layer2 only rows attention reads ----
    const int spmm_grid = N_NODE / 8;   // 12500, exact
    spmm_bf16<<<spmm_grid, 256, 0, stream>>>(ebf0, csr_cv, row_start, counts,
                                             needed, 0, ebf1);
    spmm_bf16<<<spmm_grid, 256, 0, stream>>>(ebf1, csr_cv, row_start, counts,
                                             needed, 1, ebf2);

    // ---- attention ----
    gather_project<<<NROWS / GP_ROWS, 256, 0, stream>>>(embedding, ebf1, ebf2,
                                                        session_item, W_q, W_k,
                                                        seqws, Qws, Kws);
    attn_score_pool<<<BATCH, 256, 0, stream>>>(Qws, Kws, seqws, session_len, mask,
                                               seqh, acc2);

    // ---- session graph ----
    gemm_DA<<<dim3(16, 16), 256, 0, stream>>>(D, A, DAb);
    sess_linear<<<BATCH, 128, 0, stream>>>(seqh, w_sess + 0 * EMB * EMB, tbuf);
    sess_prop  <<<BATCH, 128, 0, stream>>>(DAb, tbuf, sbuf, acc2, out, 0);
    sess_linear<<<BATCH, 128, 0, stream>>>(sbuf, w_sess + 1 * EMB * EMB, tbuf);
    sess_prop  <<<BATCH, 128, 0, stream>>>(DAb, tbuf, sbuf, acc2, out, 1);
}

// Round 7
// 497.345 us; speedup vs baseline: 1.5460x; 1.2018x over previous
//
#include <hip/hip_runtime.h>

#define N_NODE 100000
#define EMB 112
#define BATCH 512
#define SEQL 50
#define NNZ 1600000
#define NROWS (BATCH * SEQL)          // 25600 flattened session slots

#define NBUCK ((N_NODE + 63) / 64)    // 1563 buckets of 64 rows
#define BUCK_CAP 1536                 // mean 1024, sd 32 -> 16 sigma headroom
#define TILE_E 8192
#define P1_BLOCKS ((NNZ + TILE_E - 1) / TILE_E)   // 196

__device__ __forceinline__ float bf2f(unsigned short u) {
    return __uint_as_float((unsigned)u << 16);
}
__device__ __forceinline__ unsigned short f2bf(float f) {
    unsigned u = __float_as_uint(f);
    return (unsigned short)((u + 0x7FFF + ((u >> 16) & 1)) >> 16);   // RNE
}

// ---------------- fp32 -> bf16 table copy ----------------------------------
__global__ __launch_bounds__(256) void to_bf16(
    const float* __restrict__ in, unsigned short* __restrict__ out)
{
    int i = blockIdx.x * 256 + threadIdx.x;          // one float4 -> ushort4
    const int n4 = N_NODE * EMB / 4;
    if (i >= n4) return;
    float4 v = ((const float4*)in)[i];
    ushort4 o;
    o.x = f2bf(v.x); o.y = f2bf(v.y); o.z = f2bf(v.z); o.w = f2bf(v.w);
    ((ushort4*)out)[i] = o;
}

// ---- phase 1: block-aggregated binning into 64-row bucket regions ---------
// Per block: LDS histogram over all 1563 buckets, ONE global reservation per
// (block,bucket), then LDS-cursor scatter. Avoids per-edge global contention.
__global__ __launch_bounds__(256) void edge_bin(
    const int* __restrict__ rows, const int* __restrict__ cols,
    const float* __restrict__ vals,
    int* __restrict__ bcur, uint2* __restrict__ staged)
{
    __shared__ int hist[NBUCK];
    const int t = threadIdx.x;
    const int e0 = blockIdx.x * TILE_E;
    const int e1 = (e0 + TILE_E < NNZ) ? e0 + TILE_E : NNZ;

    for (int i = t; i < NBUCK; i += 256) hist[i] = 0;
    __syncthreads();
    for (int e = e0 + t; e < e1; e += 256)
        atomicAdd(&hist[rows[e] >> 6], 1);
    __syncthreads();
    // reserve this block's span in each non-empty bucket; hist becomes cursor
    for (int i = t; i < NBUCK; i += 256) {
        int c = hist[i];
        hist[i] = (c > 0) ? atomicAdd(&bcur[i], c) : 0;
    }
    __syncthreads();
    for (int e = e0 + t; e < e1; e += 256) {
        int r = rows[e];
        int b = r >> 6;
        int k = atomicAdd(&hist[b], 1);
        uint2 s;
        s.x = ((unsigned)(r & 63) << 26) | (unsigned)cols[e];
        s.y = __float_as_uint(vals[e]);
        staged[(size_t)b * BUCK_CAP + k] = s;
    }
}

// ---- phase 2: bucket-local CSR finalize (count+scan+scatter in LDS) -------
// One block per bucket; all global writes confined to a 12 KB L2 window.
// Emits row_start/counts directly -- no global scan needed.
__global__ __launch_bounds__(256) void bucket_build(
    const uint2* __restrict__ staged, const int* __restrict__ bcur,
    int2* __restrict__ csr_cv, int* __restrict__ row_start,
    int* __restrict__ counts)
{
    __shared__ int cnt[64];
    const int b = blockIdx.x;
    const int t = threadIdx.x;
    const int n = bcur[b];
    const size_t base = (size_t)b * BUCK_CAP;
    const int r0 = b << 6;

    if (t < 64) cnt[t] = 0;
    __syncthreads();
    for (int i = t; i < n; i += 256)
        atomicAdd(&cnt[staged[base + i].x >> 26], 1);
    __syncthreads();

    if (t < 64) {                       // wave 0: exclusive scan of 64 counts
        int c = cnt[t];
        int x = c;
        for (int o = 1; o < 64; o <<= 1) {
            int y = __shfl_up(x, o);
            if (t >= o) x += y;
        }
        int excl = x - c;
        int row = r0 + t;
        if (row < N_NODE) {
            row_start[row] = (int)base + excl;
            counts[row] = c;
        }
        cnt[t] = excl;                  // reuse as per-row cursor
    }
    __syncthreads();
    for (int i = t; i < n; i += 256) {
        uint2 s = staged[base + i];
        int rl = s.x >> 26;
        int k = atomicAdd(&cnt[rl], 1);
        int2 cv;
        cv.x = (int)(s.x & 0x03FFFFFFu);
        cv.y = (int)s.y;
        csr_cv[base + k] = cv;
    }
}

// mark rows of the embedding table that attention will actually read
__global__ __launch_bounds__(256) void mark_needed(
    const int* __restrict__ items, int* __restrict__ needed)
{
    int i = blockIdx.x * 256 + threadIdx.x;
    if (i >= NROWS) return;
    int g = items[i];
    if (g > 0) needed[g - 1] = 1;     // benign races, all write 1
}

// ---------------- HyperConv layer: bf16 gather, 2 rows per wave ------------
// half-wave (32 lanes) per row; lanes 0..27 own ushort4 feature chunks.
__global__ __launch_bounds__(256) void spmm_bf16(
    const unsigned short* __restrict__ src, const int2* __restrict__ csr_cv,
    const int* __restrict__ row_start, const int* __restrict__ counts,
    const int* __restrict__ needed, int use_needed,
    unsigned short* __restrict__ dst)
{
    const int lane = threadIdx.x & 63;
    const int wave = threadIdx.x >> 6;
    const int half = lane >> 5;
    const int hl = lane & 31;
    const int row = blockIdx.x * 8 + wave * 2 + half;   // grid covers exactly N_NODE
    const bool act = hl < 28;
    const int d0 = hl * 4;

    const bool skip = use_needed && (needed[row] == 0);
    int n = skip ? 0 : counts[row];
    const int beg = row_start[row];

    float a0 = 0.f, a1 = 0.f, a2 = 0.f, a3 = 0.f;
    int i = 0;
    for (; i + 8 <= n; i += 8) {
        #pragma unroll
        for (int j = 0; j < 8; ++j) {
            int2 cv = csr_cv[beg + i + j];
            float v = __int_as_float(cv.y);
            if (act) {
                ushort4 u = *(const ushort4*)(src + (size_t)cv.x * EMB + d0);
                a0 += v * bf2f(u.x);
                a1 += v * bf2f(u.y);
                a2 += v * bf2f(u.z);
                a3 += v * bf2f(u.w);
            }
        }
    }
    for (; i < n; ++i) {
        int2 cv = csr_cv[beg + i];
        float v = __int_as_float(cv.y);
        if (act) {
            ushort4 u = *(const ushort4*)(src + (size_t)cv.x * EMB + d0);
            a0 += v * bf2f(u.x);
            a1 += v * bf2f(u.y);
            a2 += v * bf2f(u.z);
            a3 += v * bf2f(u.w);
        }
    }
    if (act && !skip) {
        ushort4 o;
        o.x = f2bf(a0); o.y = f2bf(a1); o.z = f2bf(a2); o.w = f2bf(a3);
        *(ushort4*)(dst + (size_t)row * EMB + d0) = o;
    }
}

// ---------------- gather + Q/K projection (register-tiled) -----------------
#define GP_ROWS 32
#define SEQ_PAD 116
__global__ __launch_bounds__(256) void gather_project(
    const float* __restrict__ emb0,
    const unsigned short* __restrict__ e1b, const unsigned short* __restrict__ e2b,
    const int* __restrict__ items,
    const float* __restrict__ Wq, const float* __restrict__ Wk,
    float* __restrict__ seqws, float* __restrict__ Qws, float* __restrict__ Kws)
{
    __shared__ float s_seq[GP_ROWS][SEQ_PAD];
    const int t = threadIdx.x;
    const int R0 = blockIdx.x * GP_ROWS;

    for (int idx = t; idx < GP_ROWS * EMB; idx += 256) {
        int r = idx / EMB, d = idx - r * EMB;
        int g = items[R0 + r];
        float v = 0.f;
        if (g > 0) {
            size_t off = (size_t)(g - 1) * EMB + d;
            v = (emb0[off] + bf2f(e1b[off]) + bf2f(e2b[off])) * (1.f / 3.f);
        }
        s_seq[r][d] = v;
        seqws[(size_t)(R0 + r) * EMB + d] = v;
    }
    __syncthreads();

    if (t >= 224) return;
    const int rg = t / 28;
    const int e0 = (t % 28) * 4;

    float accq[4][4] = {{0.f}}, acck[4][4] = {{0.f}};
    for (int d4 = 0; d4 < 28; ++d4) {
        float sa[4][4];
        #pragma unroll
        for (int rr = 0; rr < 4; ++rr) {
            float4 v = *(const float4*)&s_seq[rg * 4 + rr][d4 * 4];
            sa[rr][0] = v.x; sa[rr][1] = v.y; sa[rr][2] = v.z; sa[rr][3] = v.w;
        }
        #pragma unroll
        for (int j = 0; j < 4; ++j) {
            const int d = d4 * 4 + j;
            float4 wq = *(const float4*)&Wq[d * EMB + e0];
            float4 wk = *(const float4*)&Wk[d * EMB + e0];
            #pragma unroll
            for (int rr = 0; rr < 4; ++rr) {
                float s = sa[rr][j];
                accq[rr][0] += s * wq.x; accq[rr][1] += s * wq.y;
                accq[rr][2] += s * wq.z; accq[rr][3] += s * wq.w;
                acck[rr][0] += s * wk.x; acck[rr][1] += s * wk.y;
                acck[rr][2] += s * wk.z; acck[rr][3] += s * wk.w;
            }
        }
    }
    #pragma unroll
    for (int rr = 0; rr < 4; ++rr) {
        size_t o = (size_t)(R0 + rg * 4 + rr) * EMB + e0;
        float4 q, k;
        q.x = 1.f / (1.f + __expf(-accq[rr][0]));
        q.y = 1.f / (1.f + __expf(-accq[rr][1]));
        q.z = 1.f / (1.f + __expf(-accq[rr][2]));
        q.w = 1.f / (1.f + __expf(-accq[rr][3]));
        k.x = 1.f / (1.f + __expf(-acck[rr][0]));
        k.y = 1.f / (1.f + __expf(-acck[rr][1]));
        k.z = 1.f / (1.f + __expf(-acck[rr][2]));
        k.w = 1.f / (1.f + __expf(-acck[rr][3]));
        *(float4*)&Qws[o] = q;
        *(float4*)&Kws[o] = k;
    }
}

// ---------------- scores + softmax + pooling (no LDS atomics) --------------
__global__ __launch_bounds__(256) void attn_score_pool(
    const float* __restrict__ Qws, const float* __restrict__ Kws,
    const float* __restrict__ seqws,
    const int* __restrict__ session_len, const float* __restrict__ mask,
    float* __restrict__ seq_h, float* __restrict__ acc2)
{
    __shared__ float sQ[SEQL][SEQ_PAD];
    __shared__ float sK[SEQL][SEQ_PAD];
    __shared__ float s_part[SEQL][4];
    __shared__ float s_mask[SEQL];
    __shared__ float s_beta[SEQL];

    const int b = blockIdx.x;
    const int t = threadIdx.x;

    for (int idx = t; idx < SEQL * (EMB / 4); idx += 256) {
        int l = idx / (EMB / 4), d4 = idx - l * (EMB / 4);
        *(float4*)&sQ[l][d4 * 4] = *(const float4*)&Qws[((size_t)b * SEQL + l) * EMB + d4 * 4];
        *(float4*)&sK[l][d4 * 4] = *(const float4*)&Kws[((size_t)b * SEQL + l) * EMB + d4 * 4];
    }
    if (t < SEQL) s_mask[t] = mask[b * SEQL + t];
    __syncthreads();

    const float inv_sqrt_d = rsqrtf((float)EMB);
    if (t < 200) {
        const int l = t >> 2;
        const int m0 = t & 3;
        float partial = 0.f;
        if (s_mask[l] != 0.f) {
            for (int m = m0; m < SEQL; m += 4) {
                if (m == l || s_mask[m] == 0.f) continue;
                float dot = 0.f;
                for (int d4 = 0; d4 < EMB / 4; ++d4) {
                    float4 a = *(const float4*)&sQ[l][d4 * 4];
                    float4 c = *(const float4*)&sK[m][d4 * 4];
                    dot += a.x * c.x + a.y * c.y + a.z * c.z + a.w * c.w;
                }
                partial += inv_sqrt_d / (1.f + __expf(-dot));
            }
        }
        s_part[l][m0] = partial;
    }
    __syncthreads();

    if (t < 64) {
        float slen = (float)session_len[b];
        float a = -1e30f;
        if (t < SEQL && s_mask[t] > 0.f)
            a = (s_part[t][0] + s_part[t][1] + s_part[t][2] + s_part[t][3]) / slen;
        float mx = a;
        for (int o = 32; o > 0; o >>= 1) mx = fmaxf(mx, __shfl_xor(mx, o));
        float ex = __expf(a - mx);
        float sm = ex;
        for (int o = 32; o > 0; o >>= 1) sm += __shfl_xor(sm, o);
        if (t < SEQL) s_beta[t] = ex / sm;
    }
    __syncthreads();

    if (t < EMB) {
        float h = 0.f;
        for (int l = 0; l < SEQL; ++l)
            h += s_beta[l] * seqws[((size_t)b * SEQL + l) * EMB + t];
        seq_h[b * EMB + t] = h;
        acc2[b * EMB + t] = h;
    }
}

// ---------------- DA = D @ A  (32x32 LDS-tiled) ----------------------------
__global__ __launch_bounds__(256) void gemm_DA(
    const float* __restrict__ D, const float* __restrict__ A,
    float* __restrict__ DA)
{
    __shared__ float sD[32][33];
    __shared__ float sA[32][33];
    const int tx = threadIdx.x & 15;
    const int ty = threadIdx.x >> 4;
    const int i0 = blockIdx.y * 32;
    const int j0 = blockIdx.x * 32;
    float a00 = 0.f, a01 = 0.f, a10 = 0.f, a11 = 0.f;
    for (int k0 = 0; k0 < BATCH; k0 += 32) {
        for (int idx = threadIdx.x; idx < 1024; idx += 256) {
            int r = idx >> 5, c = idx & 31;
            sD[r][c] = D[(i0 + r) * BATCH + k0 + c];
            sA[r][c] = A[(k0 + r) * BATCH + j0 + c];
        }
        __syncthreads();
        #pragma unroll 8
        for (int kk = 0; kk < 32; ++kk) {
            float d0 = sD[2 * ty][kk], d1 = sD[2 * ty + 1][kk];
            float b0 = sA[kk][2 * tx], b1 = sA[kk][2 * tx + 1];
            a00 += d0 * b0; a01 += d0 * b1;
            a10 += d1 * b0; a11 += d1 * b1;
        }
        __syncthreads();
    }
    DA[(i0 + 2 * ty) * BATCH + j0 + 2 * tx] = a00;
    DA[(i0 + 2 * ty) * BATCH + j0 + 2 * tx + 1] = a01;
    DA[(i0 + 2 * ty + 1) * BATCH + j0 + 2 * tx] = a10;
    DA[(i0 + 2 * ty + 1) * BATCH + j0 + 2 * tx + 1] = a11;
}

// ---------------- t = s @ W^T ----------------------------------------------
__global__ __launch_bounds__(128) void sess_linear(
    const float* __restrict__ s, const float* __restrict__ W,
    float* __restrict__ t)
{
    __shared__ float s_row[EMB];
    int b = blockIdx.x;
    int e = threadIdx.x;
    if (e < EMB) s_row[e] = s[b * EMB + e];
    __syncthreads();
    if (e >= EMB) return;
    float acc = 0.f;
    for (int d = 0; d < EMB; ++d) acc += s_row[d] * W[e * EMB + d];
    t[b * EMB + e] = acc;
}

// ---------------- s = DA @ t; acc2 += s/||s||; last: out = acc2/3 ----------
__global__ __launch_bounds__(128) void sess_prop(
    const float* __restrict__ DA, const float* __restrict__ t,
    float* __restrict__ s_out, float* __restrict__ acc2,
    float* __restrict__ out, int is_last)
{
    __shared__ float s_da[BATCH];
    __shared__ float s_sq[128];
    int b = blockIdx.x;
    int e = threadIdx.x;
    for (int k = e; k < BATCH; k += 128) s_da[k] = DA[b * BATCH + k];
    __syncthreads();

    float v = 0.f;
    if (e < EMB) {
        for (int k = 0; k < BATCH; ++k) v += s_da[k] * t[k * EMB + e];
    }
    s_sq[e] = (e < EMB) ? v * v : 0.f;
    __syncthreads();
    for (int off = 64; off > 0; off >>= 1) {
        if (e < off) s_sq[e] += s_sq[e + off];
        __syncthreads();
    }
    float nrm = fmaxf(sqrtf(s_sq[0]), 1e-12f);
    if (e < EMB) {
        float a = acc2[b * EMB + e] + v / nrm;
        acc2[b * EMB + e] = a;
        s_out[b * EMB + e] = v;
        if (is_last) out[b * EMB + e] = a * (1.f / 3.f);
    }
}

extern "C" void kernel_launch(void* const* d_in, const int* in_sizes, int n_in,
                              void* d_out, int out_size, void* d_ws, size_t ws_size,
                              hipStream_t stream)
{
    (void)in_sizes; (void)n_in; (void)out_size; (void)ws_size;

    const float* embedding    = (const float*)d_in[0];
    const float* adj_vals     = (const float*)d_in[1];
    const float* W_q          = (const float*)d_in[2];
    const float* W_k          = (const float*)d_in[3];
    const float* w_sess       = (const float*)d_in[4];
    const float* D            = (const float*)d_in[5];
    const float* A            = (const float*)d_in[6];
    const int*   adj_rows     = (const int*)d_in[7];
    const int*   adj_cols     = (const int*)d_in[8];
    const int*   session_item = (const int*)d_in[9];
    const int*   session_len  = (const int*)d_in[10];
    const float* mask         = (const float*)d_in[11];
    float* out = (float*)d_out;

    // ---- workspace layout ----
    unsigned short* ebf0 = (unsigned short*)d_ws;                 // 3 x 11.2M ushort
    unsigned short* ebf1 = ebf0 + (size_t)N_NODE * EMB;
    unsigned short* ebf2 = ebf1 + (size_t)N_NODE * EMB;
    float* DAb       = (float*)(ebf2 + (size_t)N_NODE * EMB);     // 8B-aligned
    float* seqh      = DAb  + (size_t)BATCH * BATCH;
    float* acc2      = seqh + (size_t)BATCH * EMB;
    float* tbuf      = acc2 + (size_t)BATCH * EMB;
    float* sbuf      = tbuf + (size_t)BATCH * EMB;
    float* seqws     = sbuf + (size_t)BATCH * EMB;                // 34.4 MB region
    float* Qws       = seqws + (size_t)NROWS * EMB;
    float* Kws       = Qws   + (size_t)NROWS * EMB;
    int*   counts    = (int*)(Kws + (size_t)NROWS * EMB);
    int*   needed    = counts + N_NODE;
    int*   row_start = needed + N_NODE;
    int*   bcur      = row_start + N_NODE;                        // NBUCK, pad 2048
    int2*  csr_cv    = (int2*)(bcur + 2048);                      // NBUCK*BUCK_CAP = 19.2 MB
    // staged aliases seqws/Qws/Kws (dead before gather_project writes them)
    uint2* staged    = (uint2*)seqws;                             // 19.2 MB < 34.4 MB

    // needed + bcur need zeroing (adjacent-ish: two small memsets)
    hipMemsetAsync(needed, 0, N_NODE * sizeof(int), stream);
    hipMemsetAsync(bcur, 0, 2048 * sizeof(int), stream);

    // ---- bf16 copy of the embedding table ----
    to_bf16<<<(N_NODE * EMB / 4 + 255) / 256, 256, 0, stream>>>(embedding, ebf0);

    // ---- build CSR: two-phase block-aggregated bucket build ----
    edge_bin<<<P1_BLOCKS, 256, 0, stream>>>(adj_rows, adj_cols, adj_vals,
                                            bcur, staged);
    bucket_build<<<NBUCK, 256, 0, stream>>>(staged, bcur, csr_cv,
                                            row_start, counts);
    mark_needed<<<(NROWS + 255) / 256, 256, 0, stream>>>(session_item, needed);

    // ---- hyperconv: layer1 all rows, layer2 only rows attention reads ----
    const int spmm_grid = N_NODE / 8;   // 12500, exact
    spmm_bf16<<<spmm_grid, 256, 0, stream>>>(ebf0, csr_cv, row_start, counts,
                                             needed, 0, ebf1);
    spmm_bf16<<<spmm_grid, 256, 0, stream>>>(ebf1, csr_cv, row_start, counts,
                                             needed, 1, ebf2);

    // ---- attention ----
    gather_project<<<NROWS / GP_ROWS, 256, 0, stream>>>(embedding, ebf1, ebf2,
                                                        session_item, W_q, W_k,
                                                        seqws, Qws, Kws);
    attn_score_pool<<<BATCH, 256, 0, stream>>>(Qws, Kws, seqws, session_len, mask,
                                               seqh, acc2);

    // ---- session graph ----
    gemm_DA<<<dim3(16, 16), 256, 0, stream>>>(D, A, DAb);
    sess_linear<<<BATCH, 128, 0, stream>>>(seqh, w_sess + 0 * EMB * EMB, tbuf);
    sess_prop  <<<BATCH, 128, 0, stream>>>(DAb, tbuf, sbuf, acc2, out, 0);
    sess_linear<<<BATCH, 128, 0, stream>>>(sbuf, w_sess + 1 * EMB * EMB, tbuf);
    sess_prop  <<<BATCH, 128, 0, stream>>>(DAb, tbuf, sbuf, acc2, out, 1);
}

// Round 8
// 433.937 us; speedup vs baseline: 1.7719x; 1.1461x over previous
//
#include <hip/hip_runtime.h>

#define N_NODE 100000
#define EMB 112
#define EMBP 128                      // padded bf16 row: 256 B, line-aligned
#define BATCH 512
#define SEQL 50
#define NNZ 1600000
#define NROWS (BATCH * SEQL)          // 25600 flattened session slots

#define NBUCK ((N_NODE + 63) / 64)    // 1563 buckets of 64 rows
#define BUCK_CAP 1536                 // mean 1024, sd 32 -> 16 sigma headroom
#define TILE_E 8192
#define P1_BLOCKS ((NNZ + TILE_E - 1) / TILE_E)   // 196

__device__ __forceinline__ float bf2f(unsigned short u) {
    return __uint_as_float((unsigned)u << 16);
}
__device__ __forceinline__ unsigned short f2bf(float f) {
    unsigned u = __float_as_uint(f);
    return (unsigned short)((u + 0x7FFF + ((u >> 16) & 1)) >> 16);   // RNE
}

// ---------------- prep: fp32 -> padded bf16 table + mark_needed ------------
// slot = ushort4 index in padded table (32 slots/row; 28 data + 4 zero pad)
__global__ __launch_bounds__(256) void prep(
    const float* __restrict__ in, unsigned short* __restrict__ out,
    const int* __restrict__ items, int* __restrict__ needed)
{
    int i = blockIdx.x * 256 + threadIdx.x;
    int r = i >> 5, c = i & 31;
    ushort4 o; o.x = 0; o.y = 0; o.z = 0; o.w = 0;
    if (c < 28) {
        float4 v = ((const float4*)in)[r * 28 + c];
        o.x = f2bf(v.x); o.y = f2bf(v.y); o.z = f2bf(v.z); o.w = f2bf(v.w);
    }
    ((ushort4*)out)[i] = o;
    if (i < NROWS) {
        int g = items[i];
        if (g > 0) needed[g - 1] = 1;   // benign races, all write 1
    }
}

// ---- phase 1: block-aggregated binning into 64-row bucket regions ---------
__global__ __launch_bounds__(256) void edge_bin(
    const int* __restrict__ rows, const int* __restrict__ cols,
    const float* __restrict__ vals,
    int* __restrict__ bcur, uint2* __restrict__ staged)
{
    __shared__ int hist[NBUCK];
    const int t = threadIdx.x;
    const int e0 = blockIdx.x * TILE_E;
    const int e1 = (e0 + TILE_E < NNZ) ? e0 + TILE_E : NNZ;

    for (int i = t; i < NBUCK; i += 256) hist[i] = 0;
    __syncthreads();
    for (int e = e0 + t; e < e1; e += 256)
        atomicAdd(&hist[rows[e] >> 6], 1);
    __syncthreads();
    for (int i = t; i < NBUCK; i += 256) {
        int c = hist[i];
        hist[i] = (c > 0) ? atomicAdd(&bcur[i], c) : 0;
    }
    __syncthreads();
    for (int e = e0 + t; e < e1; e += 256) {
        int r = rows[e];
        int b = r >> 6;
        int k = atomicAdd(&hist[b], 1);
        uint2 s;
        s.x = ((unsigned)(r & 63) << 26) | (unsigned)cols[e];
        s.y = __float_as_uint(vals[e]);
        staged[(size_t)b * BUCK_CAP + k] = s;
    }
}

// ---- phase 2: bucket-local CSR finalize (count+scan+scatter in LDS) -------
__global__ __launch_bounds__(256) void bucket_build(
    const uint2* __restrict__ staged, const int* __restrict__ bcur,
    int2* __restrict__ csr_cv, int* __restrict__ row_start,
    int* __restrict__ counts)
{
    __shared__ int cnt[64];
    const int b = blockIdx.x;
    const int t = threadIdx.x;
    const int n = bcur[b];
    const size_t base = (size_t)b * BUCK_CAP;
    const int r0 = b << 6;

    if (t < 64) cnt[t] = 0;
    __syncthreads();
    for (int i = t; i < n; i += 256)
        atomicAdd(&cnt[staged[base + i].x >> 26], 1);
    __syncthreads();

    if (t < 64) {                       // wave 0: exclusive scan of 64 counts
        int c = cnt[t];
        int x = c;
        for (int o = 1; o < 64; o <<= 1) {
            int y = __shfl_up(x, o);
            if (t >= o) x += y;
        }
        int excl = x - c;
        int row = r0 + t;
        if (row < N_NODE) {
            row_start[row] = (int)base + excl;
            counts[row] = c;
        }
        cnt[t] = excl;                  // reuse as per-row cursor
    }
    __syncthreads();
    for (int i = t; i < n; i += 256) {
        uint2 s = staged[base + i];
        int rl = s.x >> 26;
        int k = atomicAdd(&cnt[rl], 1);
        int2 cv;
        cv.x = (int)(s.x & 0x03FFFFFFu);
        cv.y = (int)s.y;
        csr_cv[base + k] = cv;
    }
}

// ---------------- HyperConv layer: padded bf16 gather, 2 rows per wave -----
// half-wave (32 lanes) per row; every lane loads ushort4 (row = 32 x ushort4,
// exactly 2 aligned 128B lines). Pad lanes multiply zeros -> contribute 0.
__global__ __launch_bounds__(256) void spmm_bf16(
    const unsigned short* __restrict__ src, const int2* __restrict__ csr_cv,
    const int* __restrict__ row_start, const int* __restrict__ counts,
    const int* __restrict__ needed, int use_needed,
    unsigned short* __restrict__ dst)
{
    const int lane = threadIdx.x & 63;
    const int wave = threadIdx.x >> 6;
    const int half = lane >> 5;
    const int hl = lane & 31;
    const int row = blockIdx.x * 8 + wave * 2 + half;   // grid covers N_NODE
    const int d0 = hl * 4;

    const bool skip = use_needed && (needed[row] == 0);
    int n = skip ? 0 : counts[row];
    const int beg = row_start[row];

    float a0 = 0.f, a1 = 0.f, a2 = 0.f, a3 = 0.f;
    int i = 0;
    for (; i + 8 <= n; i += 8) {
        #pragma unroll
        for (int j = 0; j < 8; ++j) {
            int2 cv = csr_cv[beg + i + j];
            float v = __int_as_float(cv.y);
            ushort4 u = *(const ushort4*)(src + (size_t)cv.x * EMBP + d0);
            a0 += v * bf2f(u.x);
            a1 += v * bf2f(u.y);
            a2 += v * bf2f(u.z);
            a3 += v * bf2f(u.w);
        }
    }
    for (; i < n; ++i) {
        int2 cv = csr_cv[beg + i];
        float v = __int_as_float(cv.y);
        ushort4 u = *(const ushort4*)(src + (size_t)cv.x * EMBP + d0);
        a0 += v * bf2f(u.x);
        a1 += v * bf2f(u.y);
        a2 += v * bf2f(u.z);
        a3 += v * bf2f(u.w);
    }
    if (!skip) {
        ushort4 o;
        o.x = f2bf(a0); o.y = f2bf(a1); o.z = f2bf(a2); o.w = f2bf(a3);
        *(ushort4*)(dst + (size_t)row * EMBP + d0) = o;
    }
}

// ---------------- gather + Q/K projection (register-tiled) -----------------
#define GP_ROWS 32
#define SEQ_PAD 116
__global__ __launch_bounds__(256) void gather_project(
    const float* __restrict__ emb0,
    const unsigned short* __restrict__ e1b, const unsigned short* __restrict__ e2b,
    const int* __restrict__ items,
    const float* __restrict__ Wq, const float* __restrict__ Wk,
    float* __restrict__ seqws, float* __restrict__ Qws, float* __restrict__ Kws)
{
    __shared__ float s_seq[GP_ROWS][SEQ_PAD];
    const int t = threadIdx.x;
    const int R0 = blockIdx.x * GP_ROWS;

    for (int idx = t; idx < GP_ROWS * EMB; idx += 256) {
        int r = idx / EMB, d = idx - r * EMB;
        int g = items[R0 + r];
        float v = 0.f;
        if (g > 0) {
            size_t o32 = (size_t)(g - 1) * EMB + d;
            size_t obf = (size_t)(g - 1) * EMBP + d;
            v = (emb0[o32] + bf2f(e1b[obf]) + bf2f(e2b[obf])) * (1.f / 3.f);
        }
        s_seq[r][d] = v;
        seqws[(size_t)(R0 + r) * EMB + d] = v;
    }
    __syncthreads();

    if (t >= 224) return;
    const int rg = t / 28;
    const int e0 = (t % 28) * 4;

    float accq[4][4] = {{0.f}}, acck[4][4] = {{0.f}};
    for (int d4 = 0; d4 < 28; ++d4) {
        float sa[4][4];
        #pragma unroll
        for (int rr = 0; rr < 4; ++rr) {
            float4 v = *(const float4*)&s_seq[rg * 4 + rr][d4 * 4];
            sa[rr][0] = v.x; sa[rr][1] = v.y; sa[rr][2] = v.z; sa[rr][3] = v.w;
        }
        #pragma unroll
        for (int j = 0; j < 4; ++j) {
            const int d = d4 * 4 + j;
            float4 wq = *(const float4*)&Wq[d * EMB + e0];
            float4 wk = *(const float4*)&Wk[d * EMB + e0];
            #pragma unroll
            for (int rr = 0; rr < 4; ++rr) {
                float s = sa[rr][j];
                accq[rr][0] += s * wq.x; accq[rr][1] += s * wq.y;
                accq[rr][2] += s * wq.z; accq[rr][3] += s * wq.w;
                acck[rr][0] += s * wk.x; acck[rr][1] += s * wk.y;
                acck[rr][2] += s * wk.z; acck[rr][3] += s * wk.w;
            }
        }
    }
    #pragma unroll
    for (int rr = 0; rr < 4; ++rr) {
        size_t o = (size_t)(R0 + rg * 4 + rr) * EMB + e0;
        float4 q, k;
        q.x = 1.f / (1.f + __expf(-accq[rr][0]));
        q.y = 1.f / (1.f + __expf(-accq[rr][1]));
        q.z = 1.f / (1.f + __expf(-accq[rr][2]));
        q.w = 1.f / (1.f + __expf(-accq[rr][3]));
        k.x = 1.f / (1.f + __expf(-acck[rr][0]));
        k.y = 1.f / (1.f + __expf(-acck[rr][1]));
        k.z = 1.f / (1.f + __expf(-acck[rr][2]));
        k.w = 1.f / (1.f + __expf(-acck[rr][3]));
        *(float4*)&Qws[o] = q;
        *(float4*)&Kws[o] = k;
    }
}

// ---------------- scores + softmax + pooling (no LDS atomics) --------------
__global__ __launch_bounds__(256) void attn_score_pool(
    const float* __restrict__ Qws, const float* __restrict__ Kws,
    const float* __restrict__ seqws,
    const int* __restrict__ session_len, const float* __restrict__ mask,
    float* __restrict__ seq_h, float* __restrict__ acc2)
{
    __shared__ float sQ[SEQL][SEQ_PAD];
    __shared__ float sK[SEQL][SEQ_PAD];
    __shared__ float s_part[SEQL][4];
    __shared__ float s_mask[SEQL];
    __shared__ float s_beta[SEQL];

    const int b = blockIdx.x;
    const int t = threadIdx.x;

    for (int idx = t; idx < SEQL * (EMB / 4); idx += 256) {
        int l = idx / (EMB / 4), d4 = idx - l * (EMB / 4);
        *(float4*)&sQ[l][d4 * 4] = *(const float4*)&Qws[((size_t)b * SEQL + l) * EMB + d4 * 4];
        *(float4*)&sK[l][d4 * 4] = *(const float4*)&Kws[((size_t)b * SEQL + l) * EMB + d4 * 4];
    }
    if (t < SEQL) s_mask[t] = mask[b * SEQL + t];
    __syncthreads();

    const float inv_sqrt_d = rsqrtf((float)EMB);
    if (t < 200) {
        const int l = t >> 2;
        const int m0 = t & 3;
        float partial = 0.f;
        if (s_mask[l] != 0.f) {
            for (int m = m0; m < SEQL; m += 4) {
                if (m == l || s_mask[m] == 0.f) continue;
                float dot = 0.f;
                for (int d4 = 0; d4 < EMB / 4; ++d4) {
                    float4 a = *(const float4*)&sQ[l][d4 * 4];
                    float4 c = *(const float4*)&sK[m][d4 * 4];
                    dot += a.x * c.x + a.y * c.y + a.z * c.z + a.w * c.w;
                }
                partial += inv_sqrt_d / (1.f + __expf(-dot));
            }
        }
        s_part[l][m0] = partial;
    }
    __syncthreads();

    if (t < 64) {
        float slen = (float)session_len[b];
        float a = -1e30f;
        if (t < SEQL && s_mask[t] > 0.f)
            a = (s_part[t][0] + s_part[t][1] + s_part[t][2] + s_part[t][3]) / slen;
        float mx = a;
        for (int o = 32; o > 0; o >>= 1) mx = fmaxf(mx, __shfl_xor(mx, o));
        float ex = __expf(a - mx);
        float sm = ex;
        for (int o = 32; o > 0; o >>= 1) sm += __shfl_xor(sm, o);
        if (t < SEQL) s_beta[t] = ex / sm;
    }
    __syncthreads();

    if (t < EMB) {
        float h = 0.f;
        for (int l = 0; l < SEQL; ++l)
            h += s_beta[l] * seqws[((size_t)b * SEQL + l) * EMB + t];
        seq_h[b * EMB + t] = h;
        acc2[b * EMB + t] = h;
    }
}

// ---------------- DA = D @ A  (32x32 LDS-tiled) ----------------------------
__global__ __launch_bounds__(256) void gemm_DA(
    const float* __restrict__ D, const float* __restrict__ A,
    float* __restrict__ DA)
{
    __shared__ float sD[32][33];
    __shared__ float sA[32][33];
    const int tx = threadIdx.x & 15;
    const int ty = threadIdx.x >> 4;
    const int i0 = blockIdx.y * 32;
    const int j0 = blockIdx.x * 32;
    float a00 = 0.f, a01 = 0.f, a10 = 0.f, a11 = 0.f;
    for (int k0 = 0; k0 < BATCH; k0 += 32) {
        for (int idx = threadIdx.x; idx < 1024; idx += 256) {
            int r = idx >> 5, c = idx & 31;
            sD[r][c] = D[(i0 + r) * BATCH + k0 + c];
            sA[r][c] = A[(k0 + r) * BATCH + j0 + c];
        }
        __syncthreads();
        #pragma unroll 8
        for (int kk = 0; kk < 32; ++kk) {
            float d0 = sD[2 * ty][kk], d1 = sD[2 * ty + 1][kk];
            float b0 = sA[kk][2 * tx], b1 = sA[kk][2 * tx + 1];
            a00 += d0 * b0; a01 += d0 * b1;
            a10 += d1 * b0; a11 += d1 * b1;
        }
        __syncthreads();
    }
    DA[(i0 + 2 * ty) * BATCH + j0 + 2 * tx] = a00;
    DA[(i0 + 2 * ty) * BATCH + j0 + 2 * tx + 1] = a01;
    DA[(i0 + 2 * ty + 1) * BATCH + j0 + 2 * tx] = a10;
    DA[(i0 + 2 * ty + 1) * BATCH + j0 + 2 * tx + 1] = a11;
}

// ---------------- t = s @ W^T ----------------------------------------------
__global__ __launch_bounds__(128) void sess_linear(
    const float* __restrict__ s, const float* __restrict__ W,
    float* __restrict__ t)
{
    __shared__ float s_row[EMB];
    int b = blockIdx.x;
    int e = threadIdx.x;
    if (e < EMB) s_row[e] = s[b * EMB + e];
    __syncthreads();
    if (e >= EMB) return;
    float acc = 0.f;
    for (int d = 0; d < EMB; ++d) acc += s_row[d] * W[e * EMB + d];
    t[b * EMB + e] = acc;
}

// ---------------- s = DA @ t; acc2 += s/||s||; last: out = acc2/3 ----------
__global__ __launch_bounds__(128) void sess_prop(
    const float* __restrict__ DA, const float* __restrict__ t,
    float* __restrict__ s_out, float* __restrict__ acc2,
    float* __restrict__ out, int is_last)
{
    __shared__ float s_da[BATCH];
    __shared__ float s_sq[128];
    int b = blockIdx.x;
    int e = threadIdx.x;
    for (int k = e; k < BATCH; k += 128) s_da[k] = DA[b * BATCH + k];
    __syncthreads();

    float v = 0.f;
    if (e < EMB) {
        for (int k = 0; k < BATCH; ++k) v += s_da[k] * t[k * EMB + e];
    }
    s_sq[e] = (e < EMB) ? v * v : 0.f;
    __syncthreads();
    for (int off = 64; off > 0; off >>= 1) {
        if (e < off) s_sq[e] += s_sq[e + off];
        __syncthreads();
    }
    float nrm = fmaxf(sqrtf(s_sq[0]), 1e-12f);
    if (e < EMB) {
        float a = acc2[b * EMB + e] + v / nrm;
        acc2[b * EMB + e] = a;
        s_out[b * EMB + e] = v;
        if (is_last) out[b * EMB + e] = a * (1.f / 3.f);
    }
}

extern "C" void kernel_launch(void* const* d_in, const int* in_sizes, int n_in,
                              void* d_out, int out_size, void* d_ws, size_t ws_size,
                              hipStream_t stream)
{
    (void)in_sizes; (void)n_in; (void)out_size; (void)ws_size;

    const float* embedding    = (const float*)d_in[0];
    const float* adj_vals     = (const float*)d_in[1];
    const float* W_q          = (const float*)d_in[2];
    const float* W_k          = (const float*)d_in[3];
    const float* w_sess       = (const float*)d_in[4];
    const float* D            = (const float*)d_in[5];
    const float* A            = (const float*)d_in[6];
    const int*   adj_rows     = (const int*)d_in[7];
    const int*   adj_cols     = (const int*)d_in[8];
    const int*   session_item = (const int*)d_in[9];
    const int*   session_len  = (const int*)d_in[10];
    const float* mask         = (const float*)d_in[11];
    float* out = (float*)d_out;

    // ---- workspace layout ----
    unsigned short* ebf0 = (unsigned short*)d_ws;                 // 3 x 12.8M ushort (padded)
    unsigned short* ebf1 = ebf0 + (size_t)N_NODE * EMBP;
    unsigned short* ebf2 = ebf1 + (size_t)N_NODE * EMBP;
    float* DAb       = (float*)(ebf2 + (size_t)N_NODE * EMBP);    // 8B-aligned
    float* seqh      = DAb  + (size_t)BATCH * BATCH;
    float* acc2      = seqh + (size_t)BATCH * EMB;
    float* tbuf      = acc2 + (size_t)BATCH * EMB;
    float* sbuf      = tbuf + (size_t)BATCH * EMB;
    float* seqws     = sbuf + (size_t)BATCH * EMB;                // 34.4 MB region
    float* Qws       = seqws + (size_t)NROWS * EMB;
    float* Kws       = Qws   + (size_t)NROWS * EMB;
    int*   counts    = (int*)(Kws + (size_t)NROWS * EMB);
    int*   row_start = counts + N_NODE;
    int*   needed    = row_start + N_NODE;                        // needed+bcur adjacent
    int*   bcur      = needed + N_NODE;                           // NBUCK, pad 2048
    int2*  csr_cv    = (int2*)(bcur + 2048);                      // NBUCK*BUCK_CAP = 19.2 MB
    // staged aliases seqws/Qws/Kws (dead before gather_project writes them)
    uint2* staged    = (uint2*)seqws;                             // 19.2 MB < 34.4 MB

    // one memset covers needed + bcur (adjacent)
    hipMemsetAsync(needed, 0, (N_NODE + 2048) * sizeof(int), stream);

    // ---- prep: padded bf16 table + mark_needed (fused) ----
    prep<<<N_NODE * 32 / 256, 256, 0, stream>>>(embedding, ebf0,
                                                session_item, needed);

    // ---- build CSR: two-phase block-aggregated bucket build ----
    edge_bin<<<P1_BLOCKS, 256, 0, stream>>>(adj_rows, adj_cols, adj_vals,
                                            bcur, staged);
    bucket_build<<<NBUCK, 256, 0, stream>>>(staged, bcur, csr_cv,
                                            row_start, counts);

    // ---- hyperconv: layer1 all rows, layer2 only rows attention reads ----
    const int spmm_grid = N_NODE / 8;   // 12500, exact
    spmm_bf16<<<spmm_grid, 256, 0, stream>>>(ebf0, csr_cv, row_start, counts,
                                             needed, 0, ebf1);
    spmm_bf16<<<spmm_grid, 256, 0, stream>>>(ebf1, csr_cv, row_start, counts,
                                             needed, 1, ebf2);

    // ---- attention ----
    gather_project<<<NROWS / GP_ROWS, 256, 0, stream>>>(embedding, ebf1, ebf2,
                                                        session_item, W_q, W_k,
                                                        seqws, Qws, Kws);
    attn_score_pool<<<BATCH, 256, 0, stream>>>(Qws, Kws, seqws, session_len, mask,
                                               seqh, acc2);

    // ---- session graph ----
    gemm_DA<<<dim3(16, 16), 256, 0, stream>>>(D, A, DAb);
    sess_linear<<<BATCH, 128, 0, stream>>>(seqh, w_sess + 0 * EMB * EMB, tbuf);
    sess_prop  <<<BATCH, 128, 0, stream>>>(DAb, tbuf, sbuf, acc2, out, 0);
    sess_linear<<<BATCH, 128, 0, stream>>>(sbuf, w_sess + 1 * EMB * EMB, tbuf);
    sess_prop  <<<BATCH, 128, 0, stream>>>(DAb, tbuf, sbuf, acc2, out, 1);
}